// Round 7
// baseline (20967.529 us; speedup 1.0000x reference)
//
#include <hip/hip_runtime.h>
#include <hip/hip_bf16.h>
#include <math.h>

// PAFM fused. Inputs fp32 in dict order (proven R5/R6); OUTPUT IS FP32
// (reference returns float32; harness allocates d_out per reference output dtype).
// Compute fp32. Geometry: B=4, DIM=128, CH=256, H=W=256, H0=W0=128, NH=8, HD=16, RD=8.
// Main kernel: 1 wave = 1 patch; 256 threads = 4 patches/block.

// ---------------- kernel 1: per-(side,b,channel) spatial mean of x_low ----------------
__global__ __launch_bounds__(256) void mean_kernel(const float* __restrict__ x_l,
                                                   const float* __restrict__ x_r,
                                                   float* __restrict__ ws_mean) {
    int bid = blockIdx.x;                       // s*1024 + b*256 + c, 2048 blocks
    const float* src = (bid >= 1024) ? x_r : x_l;
    const float* p = src + (size_t)(bid & 1023) * 16384;
    int t = threadIdx.x;
    float acc = 0.f;
    #pragma unroll 4
    for (int i = t; i < 16384; i += 256) acc += p[i];
    #pragma unroll
    for (int off = 32; off > 0; off >>= 1) acc += __shfl_down(acc, off, 64);
    __shared__ float red[4];
    if ((t & 63) == 0) red[t >> 6] = acc;
    __syncthreads();
    if (t == 0) ws_mean[bid] = (red[0] + red[1] + red[2] + red[3]) * (1.f / 16384.f);
}

// ---------------- kernel 2: channel gate cm[side][b][128] ----------------
__global__ __launch_bounds__(128) void cm_kernel(const float* __restrict__ ws_mean,
                                                 float* __restrict__ ws_cm,
                                                 const float* __restrict__ Wk,
                                                 const float* __restrict__ bk,
                                                 const float* __restrict__ d_w1,
                                                 const float* __restrict__ d_ln2_g,
                                                 const float* __restrict__ d_ln2_b,
                                                 const float* __restrict__ d_w2) {
    int sb = blockIdx.x;                        // 0..7 = s*4+b
    __shared__ float km[128];
    int o = threadIdx.x;
    const float* mu = ws_mean + sb * 256;
    float acc = bk[o];
    for (int c = 0; c < 256; ++c) acc = fmaf(Wk[o * 256 + c], mu[c], acc);
    km[o] = acc;
    __syncthreads();
    int h = o >> 4, d = o & 15;
    float t1[8];
    #pragma unroll
    for (int r = 0; r < 8; ++r) {
        float a = 0.f;
        #pragma unroll
        for (int dd = 0; dd < 16; ++dd) a = fmaf(d_w1[r * 16 + dd], km[h * 16 + dd], a);
        t1[r] = a / (1.f + expf(-a));           // silu
    }
    float m = 0.f;
    #pragma unroll
    for (int r = 0; r < 8; ++r) m += t1[r];
    m *= 0.125f;
    float v = 0.f;
    #pragma unroll
    for (int r = 0; r < 8; ++r) { float df = t1[r] - m; v = fmaf(df, df, v); }
    float rstd = rsqrtf(v * 0.125f + 1e-5f);
    float cmv = 0.f;
    #pragma unroll
    for (int r = 0; r < 8; ++r)
        cmv = fmaf((t1[r] - m) * rstd * d_ln2_g[r] + d_ln2_b[r], d_w2[d * 8 + r], cmv);
    ws_cm[sb * 128 + o] = cmv;
}

// ---------------- kernel 3: fused main, 1 wave = 1 patch ----------------
__global__ __launch_bounds__(256) void pafm_wave(
    const float* __restrict__ x_l,  const float* __restrict__ x_r,
    const float* __restrict__ x_lh, const float* __restrict__ x_rh,
    const float* __restrict__ Wq,   const float* __restrict__ bq,
    const float* __restrict__ Wqv,  const float* __restrict__ bqv,
    const float* __restrict__ Wk,   const float* __restrict__ bk,
    const float* __restrict__ Wv,   const float* __restrict__ bv,
    const float* __restrict__ Wp,   const float* __restrict__ bp,
    const float* __restrict__ ln_g, const float* __restrict__ ln_b,
    const float* __restrict__ d_ln1_g, const float* __restrict__ d_ln1_b,
    const float* __restrict__ d_wsv,   // DANE d_ws gate vector (1,16)
    const float* __restrict__ ws_cm,
    float* __restrict__ out) {

    __shared__ float buf_s[4][512];     // tgt (first 256) -> src[4][128] -> xc[4][128]
    __shared__ float k_s[4][128];
    __shared__ float v_s[4][128];
    __shared__ float q_s[4][4][128];    // [wave][px][o]
    __shared__ float vq_s[4][4][128];
    __shared__ float aw_s[4][32];       // attn weights [h*4+px]
    __shared__ float sm_s[4][8];        // DANE spatial gate per head

    int bid = blockIdx.x;               // 32768 = 2*4*128*32
    int s   = bid >> 14;
    int b   = (bid >> 12) & 3;
    int i0  = (bid >> 5) & 127;
    int jb  = bid & 31;

    int t = threadIdx.x;
    int w = t >> 6;                     // wave id 0..3
    int l = t & 63;                     // lane
    int j = jb * 4 + w;                 // patch col 0..127

    const float* xlow  = s ? x_r : x_l;
    const float* xhigh = s ? x_rh : x_lh;
    const float* g_cm  = ws_cm + (s * 4 + b) * 128;
    size_t sbase = (size_t)s * 33554432;

    // ---- A: stage target token (256 channels of x_low at (i0, j)) ----
    const float* lowp = xlow + (size_t)b * 256 * 16384 + (size_t)i0 * 128 + j;
    for (int cc = l; cc < 256; cc += 64) buf_s[w][cc] = lowp[(size_t)cc * 16384];
    __syncthreads();

    // ---- B: K, V = Wk/Wv (128x256) @ tgt ----
    #pragma unroll
    for (int half = 0; half < 2; ++half) {
        int o = l + 64 * half;
        float ka = bk[o], va = bv[o];
        #pragma unroll 4
        for (int c = 0; c < 256; ++c) {
            float tv = buf_s[w][c];
            ka = fmaf(Wk[o * 256 + c], tv, ka);
            va = fmaf(Wv[o * 256 + c], tv, va);
        }
        k_s[w][o] = ka; v_s[w][o] = va;
    }
    __syncthreads();

    // ---- C: stage 4 high-res pixels (2x2 patch), 128 channels each ----
    const float* hib = xhigh + (size_t)b * 128 * 65536;
    for (int idx = l; idx < 512; idx += 64) {
        int px = idx >> 7, c = idx & 127;
        int dy = px >> 1, dx = px & 1;
        buf_s[w][idx] = hib[(size_t)c * 65536 + (size_t)(2 * i0 + dy) * 256 + (2 * j + dx)];
    }
    __syncthreads();

    // ---- D: Q, VQ = Wq/Wqv (128x128) @ src per pixel ----
    for (int px = 0; px < 4; ++px) {
        #pragma unroll
        for (int half = 0; half < 2; ++half) {
            int o = l + 64 * half;
            float qa = bq[o], vqa = bqv[o];
            #pragma unroll 4
            for (int c = 0; c < 128; ++c) {
                float sv = buf_s[w][px * 128 + c];
                qa  = fmaf(Wq[o * 128 + c],  sv, qa);
                vqa = fmaf(Wqv[o * 128 + c], sv, vqa);
            }
            q_s[w][px][o] = qa; vq_s[w][px][o] = vqa;
        }
    }
    __syncthreads();

    // ---- E/F: attn softmax over 4 pixels + DANE spatial gate, per (h, px) ----
    {
        int hh = (l >> 2) & 7;          // head 0..7 (lanes 0..31 and 32..63 mirror)
        int px = l & 3;
        float lg = 0.f;
        #pragma unroll
        for (int d = 0; d < 16; ++d)
            lg = fmaf(q_s[w][px][hh * 16 + d], k_s[w][hh * 16 + d], lg);
        lg *= 0.25f;                    // d^-0.5, d=16
        float m1 = fmaxf(lg, __shfl_xor(lg, 1, 64));
        float mx = fmaxf(m1, __shfl_xor(m1, 2, 64));
        float e  = expf(lg - mx);
        float s1 = e + __shfl_xor(e, 1, 64);
        float s4 = s1 + __shfl_xor(s1, 2, 64);
        float awv = e / s4;
        // DANE spatial: LN(q[px][hh*16..]) . d_ws, averaged over px
        float qv[16], mn = 0.f;
        #pragma unroll
        for (int d = 0; d < 16; ++d) { qv[d] = q_s[w][px][hh * 16 + d]; mn += qv[d]; }
        mn *= (1.f / 16.f);
        float vr = 0.f;
        #pragma unroll
        for (int d = 0; d < 16; ++d) { float df = qv[d] - mn; vr = fmaf(df, df, vr); }
        float rs = rsqrtf(vr * (1.f / 16.f) + 1e-5f);
        float sd = 0.f;
        #pragma unroll
        for (int d = 0; d < 16; ++d)
            sd = fmaf((qv[d] - mn) * rs * d_ln1_g[d] + d_ln1_b[d], d_wsv[d], sd);
        float t1 = sd + __shfl_xor(sd, 1, 64);
        float smv = (t1 + __shfl_xor(t1, 2, 64)) * 0.25f;
        if (l < 32)             aw_s[w][l]  = awv;   // l = hh*4+px
        else if ((l & 3) == 0)  sm_s[w][hh] = smv;
    }
    __syncthreads();

    // ---- G: gate combine -> xc (reuse buf_s) ----
    for (int px = 0; px < 4; ++px) {
        #pragma unroll
        for (int half = 0; half < 2; ++half) {
            int o = l + 64 * half;
            int hh = o >> 4;
            float wg = 1.f / (1.f + expf(-(sm_s[w][hh] + g_cm[o])));
            float xv = (1.f - wg) * aw_s[w][hh * 4 + px] * v_s[w][o] * 4.f
                     + wg * vq_s[w][px][o];
            buf_s[w][px * 128 + o] = xv;
        }
    }
    __syncthreads();

    // ---- H: Wp projection + LayerNorm + residual + fp32 store ----
    for (int px = 0; px < 4; ++px) {
        float y0 = bp[l], y1 = bp[l + 64];
        #pragma unroll 4
        for (int c = 0; c < 128; ++c) {
            float xv = buf_s[w][px * 128 + c];
            y0 = fmaf(Wp[l * 128 + c],        xv, y0);
            y1 = fmaf(Wp[(l + 64) * 128 + c], xv, y1);
        }
        float ps = y0 + y1;
        float pq = fmaf(y0, y0, y1 * y1);
        #pragma unroll
        for (int off = 32; off; off >>= 1) {
            ps += __shfl_xor(ps, off, 64);
            pq += __shfl_xor(pq, off, 64);
        }
        float mean = ps * (1.f / 128.f);
        float var  = pq * (1.f / 128.f) - mean * mean;
        float rstd = rsqrtf(var + 1e-5f);
        int dy = px >> 1, dx = px & 1;
        size_t sp = (size_t)(2 * i0 + dy) * 256 + (size_t)(2 * j + dx);
        size_t o0 = ((size_t)b * 128 + l) * 65536 + sp;
        size_t o1 = ((size_t)b * 128 + l + 64) * 65536 + sp;
        float yn0 = (y0 - mean) * rstd * ln_g[l]      + ln_b[l];
        float yn1 = (y1 - mean) * rstd * ln_g[l + 64] + ln_b[l + 64];
        out[sbase + o0] = xhigh[o0] + yn0;
        out[sbase + o1] = xhigh[o1] + yn1;
    }
}

extern "C" void kernel_launch(void* const* d_in, const int* in_sizes, int n_in,
                              void* d_out, int out_size, void* d_ws, size_t ws_size,
                              hipStream_t stream) {
    const float* x_l   = (const float*)d_in[0];
    const float* x_r   = (const float*)d_in[1];
    const float* x_lh  = (const float*)d_in[2];
    const float* x_rh  = (const float*)d_in[3];
    const float* Wq    = (const float*)d_in[4];
    const float* bq    = (const float*)d_in[5];
    const float* Wqv   = (const float*)d_in[6];
    const float* bqv   = (const float*)d_in[7];
    const float* Wk    = (const float*)d_in[8];
    const float* bk    = (const float*)d_in[9];
    const float* Wv    = (const float*)d_in[10];
    const float* bv    = (const float*)d_in[11];
    const float* Wp    = (const float*)d_in[12];
    const float* bp    = (const float*)d_in[13];
    const float* ln_g  = (const float*)d_in[14];
    const float* ln_b  = (const float*)d_in[15];
    const float* dln1g = (const float*)d_in[16];
    const float* dln1b = (const float*)d_in[17];
    const float* d_wsv = (const float*)d_in[18];
    const float* d_w1  = (const float*)d_in[19];
    const float* dln2g = (const float*)d_in[20];
    const float* dln2b = (const float*)d_in[21];
    const float* d_w2  = (const float*)d_in[22];

    float* out = (float*)d_out;
    float* ws_mean = (float*)d_ws;            // 2048 floats
    float* ws_cm   = ws_mean + 2048;          // 1024 floats

    mean_kernel<<<2048, 256, 0, stream>>>(x_l, x_r, ws_mean);
    cm_kernel<<<8, 128, 0, stream>>>(ws_mean, ws_cm, Wk, bk, d_w1, dln2g, dln2b, d_w2);
    pafm_wave<<<32768, 256, 0, stream>>>(x_l, x_r, x_lh, x_rh,
                                         Wq, bq, Wqv, bqv, Wk, bk, Wv, bv, Wp, bp,
                                         ln_g, ln_b, dln1g, dln1b, d_wsv, ws_cm, out);
}

// Round 8
// 3950.633 us; speedup vs baseline: 5.3074x; 5.3074x over previous
//
#include <hip/hip_runtime.h>
#include <hip/hip_bf16.h>
#include <math.h>

// PAFM fused v2: thread = patch, wave-uniform scalar weights, coalesced activations.
// Inputs fp32 dict order; output fp32. Geometry: B=4, DIM=128, CH=256, H=W=256,
// H0=W0=128, NH=8, HD=16, RD=8. Grid 512 x 256thr: thread owns patch (i0, j).

__device__ __forceinline__ unsigned bf16r(float x) {
    unsigned u = __float_as_uint(x);
    return (u + 0x7FFFu + ((u >> 16) & 1u)) >> 16;
}
__device__ __forceinline__ unsigned pack2(float a, float b) {
    return bf16r(a) | (bf16r(b) << 16);
}
__device__ __forceinline__ float unpk(unsigned u, int hi) {
    return __uint_as_float(hi ? (u & 0xFFFF0000u) : (u << 16));
}

// ---------------- kernel 1: per-(side,b,channel) spatial mean of x_low ----------------
__global__ __launch_bounds__(256) void mean_kernel(const float* __restrict__ x_l,
                                                   const float* __restrict__ x_r,
                                                   float* __restrict__ ws_mean) {
    int bid = blockIdx.x;                       // s*1024 + b*256 + c, 2048 blocks
    const float* src = (bid >= 1024) ? x_r : x_l;
    const float* p = src + (size_t)(bid & 1023) * 16384;
    int t = threadIdx.x;
    float acc = 0.f;
    #pragma unroll 4
    for (int i = t; i < 16384; i += 256) acc += p[i];
    #pragma unroll
    for (int off = 32; off > 0; off >>= 1) acc += __shfl_down(acc, off, 64);
    __shared__ float red[4];
    if ((t & 63) == 0) red[t >> 6] = acc;
    __syncthreads();
    if (t == 0) ws_mean[bid] = (red[0] + red[1] + red[2] + red[3]) * (1.f / 16384.f);
}

// ---------------- kernel 2: channel gate cm[side][b][128] ----------------
__global__ __launch_bounds__(128) void cm_kernel(const float* __restrict__ ws_mean,
                                                 float* __restrict__ ws_cm,
                                                 const float* __restrict__ Wk,
                                                 const float* __restrict__ bk,
                                                 const float* __restrict__ d_w1,
                                                 const float* __restrict__ d_ln2_g,
                                                 const float* __restrict__ d_ln2_b,
                                                 const float* __restrict__ d_w2) {
    int sb = blockIdx.x;                        // 0..7 = s*4+b
    __shared__ float km[128];
    int o = threadIdx.x;
    const float* mu = ws_mean + sb * 256;
    float acc = bk[o];
    for (int c = 0; c < 256; ++c) acc = fmaf(Wk[o * 256 + c], mu[c], acc);
    km[o] = acc;
    __syncthreads();
    int h = o >> 4, d = o & 15;
    float t1[8];
    #pragma unroll
    for (int r = 0; r < 8; ++r) {
        float a = 0.f;
        #pragma unroll
        for (int dd = 0; dd < 16; ++dd) a = fmaf(d_w1[r * 16 + dd], km[h * 16 + dd], a);
        t1[r] = a / (1.f + expf(-a));           // silu
    }
    float m = 0.f;
    #pragma unroll
    for (int r = 0; r < 8; ++r) m += t1[r];
    m *= 0.125f;
    float v = 0.f;
    #pragma unroll
    for (int r = 0; r < 8; ++r) { float df = t1[r] - m; v = fmaf(df, df, v); }
    float rstd = rsqrtf(v * 0.125f + 1e-5f);
    float cmv = 0.f;
    #pragma unroll
    for (int r = 0; r < 8; ++r)
        cmv = fmaf((t1[r] - m) * rstd * d_ln2_g[r] + d_ln2_b[r], d_w2[d * 8 + r], cmv);
    ws_cm[sb * 128 + o] = cmv;
}

// ---------------- kernel 3: fused main, thread = patch ----------------
__global__ __launch_bounds__(256, 2) void pafm_patch(
    const float* __restrict__ x_l,  const float* __restrict__ x_r,
    const float* __restrict__ x_lh, const float* __restrict__ x_rh,
    const float* __restrict__ Wq,   const float* __restrict__ bq,
    const float* __restrict__ Wqv,  const float* __restrict__ bqv,
    const float* __restrict__ Wk,   const float* __restrict__ bk,
    const float* __restrict__ Wv,   const float* __restrict__ bv,
    const float* __restrict__ Wp,   const float* __restrict__ bp,
    const float* __restrict__ ln_g, const float* __restrict__ ln_b,
    const float* __restrict__ d_ln1_g, const float* __restrict__ d_ln1_b,
    const float* __restrict__ d_wsv,
    const float* __restrict__ ws_cm,
    float* __restrict__ out) {

    __shared__ unsigned xls[256 * 65];   // per-thread row: 64 dwords (128 bf16) + 1 pad

    int bid = blockIdx.x;                // 512 = 2 sides * 4 b * 64
    int s   = bid >> 8;
    int b   = (bid >> 6) & 3;
    int blk = bid & 63;
    int t   = threadIdx.x;
    int row = t >> 7;                    // 0..1
    int j   = t & 127;
    int i0  = blk * 2 + row;

    const float* xlow  = s ? x_r  : x_l;
    const float* xhigh = s ? x_rh : x_lh;
    const float* cmp   = ws_cm + (s * 4 + b) * 128;
    size_t sbase = (size_t)s * 33554432;

    const float* lowp = xlow + ((size_t)b * 256 * 128 + i0) * 128 + j;        // + c*16384
    const float* xhp  = xhigh + ((size_t)b * 128 * 256 + 2 * i0) * 256 + 2 * j; // + c*65536 + dy*256 + dx
    unsigned* myx = xls + t * 65;

    unsigned vp[64], lgp[16], awp[16];
    float sm[8];
    #pragma unroll
    for (int hh = 0; hh < 8; ++hh) sm[hh] = 0.f;
    #pragma unroll
    for (int i = 0; i < 16; ++i) lgp[i] = 0u;

    // ================= K GEMV (128 out, K=256); k -> LDS (bf16) =================
    {
        float acc[128];
        #pragma unroll
        for (int o = 0; o < 128; ++o) acc[o] = bk[o];
        for (int c0 = 0; c0 < 256; c0 += 8) {
            float a[8];
            #pragma unroll
            for (int cc = 0; cc < 8; ++cc) a[cc] = lowp[(size_t)(c0 + cc) * 16384];
            #pragma unroll
            for (int o = 0; o < 128; ++o) {
                const float* wr = Wk + (size_t)o * 256 + c0;
                #pragma unroll
                for (int cc = 0; cc < 8; ++cc) acc[o] = fmaf(wr[cc], a[cc], acc[o]);
            }
        }
        #pragma unroll
        for (int p2 = 0; p2 < 64; ++p2) myx[p2] = pack2(acc[2 * p2], acc[2 * p2 + 1]);
    }

    // ================= pass 1: per-pixel Q GEMV -> logits + DANE =================
    #pragma unroll
    for (int px = 0; px < 4; ++px) {
        const float* ap = xhp + (px >> 1) * 256 + (px & 1);
        float aq[128];
        #pragma unroll
        for (int o = 0; o < 128; ++o) aq[o] = bq[o];
        for (int c0 = 0; c0 < 128; c0 += 8) {
            float a[8];
            #pragma unroll
            for (int cc = 0; cc < 8; ++cc) a[cc] = ap[(size_t)(c0 + cc) * 65536];
            #pragma unroll
            for (int o = 0; o < 128; ++o) {
                const float* wr = Wq + (size_t)o * 128 + c0;
                #pragma unroll
                for (int cc = 0; cc < 8; ++cc) aq[o] = fmaf(wr[cc], a[cc], aq[o]);
            }
        }
        #pragma unroll
        for (int head = 0; head < 8; ++head) {
            unsigned ku[8];
            #pragma unroll
            for (int q = 0; q < 8; ++q) ku[q] = myx[head * 8 + q];
            float lg = 0.f, mn = 0.f;
            #pragma unroll
            for (int d = 0; d < 16; ++d) {
                float qd = aq[head * 16 + d];
                lg = fmaf(qd, unpk(ku[d >> 1], d & 1), lg);
                mn += qd;
            }
            lg *= 0.25f;                 // d^-0.5, d=16
            mn *= (1.f / 16.f);
            float vr = 0.f;
            #pragma unroll
            for (int d = 0; d < 16; ++d) { float df = aq[head * 16 + d] - mn; vr = fmaf(df, df, vr); }
            float rs = rsqrtf(vr * (1.f / 16.f) + 1e-5f);
            float sd = 0.f;
            #pragma unroll
            for (int d = 0; d < 16; ++d)
                sd = fmaf((aq[head * 16 + d] - mn) * rs * d_ln1_g[d] + d_ln1_b[d], d_wsv[d], sd);
            sm[head] += sd;
            int li = head * 2 + (px >> 1);
            if ((px & 1) == 0) lgp[li] = bf16r(lg);
            else               lgp[li] |= bf16r(lg) << 16;
        }
    }

    // ================= V GEMV (128 out, K=256) -> vp (bf16 regs) =================
    {
        float acc[128];
        #pragma unroll
        for (int o = 0; o < 128; ++o) acc[o] = bv[o];
        for (int c0 = 0; c0 < 256; c0 += 8) {
            float a[8];
            #pragma unroll
            for (int cc = 0; cc < 8; ++cc) a[cc] = lowp[(size_t)(c0 + cc) * 16384];
            #pragma unroll
            for (int o = 0; o < 128; ++o) {
                const float* wr = Wv + (size_t)o * 256 + c0;
                #pragma unroll
                for (int cc = 0; cc < 8; ++cc) acc[o] = fmaf(wr[cc], a[cc], acc[o]);
            }
        }
        #pragma unroll
        for (int p2 = 0; p2 < 64; ++p2) vp[p2] = pack2(acc[2 * p2], acc[2 * p2 + 1]);
    }

    // ================= softmax over px (per head) + finalize sm =================
    #pragma unroll
    for (int head = 0; head < 8; ++head) {
        float l0 = unpk(lgp[head * 2], 0),     l1 = unpk(lgp[head * 2], 1);
        float l2 = unpk(lgp[head * 2 + 1], 0), l3 = unpk(lgp[head * 2 + 1], 1);
        float mx = fmaxf(fmaxf(l0, l1), fmaxf(l2, l3));
        float e0 = __expf(l0 - mx), e1 = __expf(l1 - mx);
        float e2 = __expf(l2 - mx), e3 = __expf(l3 - mx);
        float inv = 1.f / (e0 + e1 + e2 + e3);
        awp[head * 2]     = pack2(e0 * inv, e1 * inv);
        awp[head * 2 + 1] = pack2(e2 * inv, e3 * inv);
        sm[head] *= 0.25f;
    }

    // ========== pass 2: per-pixel VQ (halves) -> gate combine -> P -> LN -> store ==========
    #pragma unroll
    for (int px = 0; px < 4; ++px) {
        const float* ap = xhp + (px >> 1) * 256 + (px & 1);
        // VQ + combine, o-halves, xc -> LDS (bf16)
        #pragma unroll
        for (int h = 0; h < 2; ++h) {
            float acc[64];
            #pragma unroll
            for (int oo = 0; oo < 64; ++oo) acc[oo] = bqv[h * 64 + oo];
            for (int c0 = 0; c0 < 128; c0 += 8) {
                float a[8];
                #pragma unroll
                for (int cc = 0; cc < 8; ++cc) a[cc] = ap[(size_t)(c0 + cc) * 65536];
                #pragma unroll
                for (int oo = 0; oo < 64; ++oo) {
                    const float* wr = Wqv + (size_t)(h * 64 + oo) * 128 + c0;
                    #pragma unroll
                    for (int cc = 0; cc < 8; ++cc) acc[oo] = fmaf(wr[cc], a[cc], acc[oo]);
                }
            }
            #pragma unroll
            for (int oo = 0; oo < 64; ++oo) {
                int o = h * 64 + oo;
                int head = o >> 4;
                float aw = unpk(awp[head * 2 + (px >> 1)], px & 1);
                float vv = unpk(vp[o >> 1], o & 1);
                float wg = 1.f / (1.f + __expf(-(sm[head] + cmp[o])));
                acc[oo] = (1.f - wg) * aw * vv * 4.f + wg * acc[oo];
            }
            #pragma unroll
            for (int p2 = 0; p2 < 32; ++p2)
                myx[h * 32 + p2] = pack2(acc[2 * p2], acc[2 * p2 + 1]);
        }
        // P GEMV from LDS xc
        unsigned yp[64];
        #pragma unroll
        for (int h = 0; h < 2; ++h) {
            float acc[64];
            #pragma unroll
            for (int oo = 0; oo < 64; ++oo) acc[oo] = bp[h * 64 + oo];
            for (int c0 = 0; c0 < 128; c0 += 8) {
                unsigned u[4];
                #pragma unroll
                for (int q = 0; q < 4; ++q) u[q] = myx[(c0 >> 1) + q];
                float a[8];
                #pragma unroll
                for (int cc = 0; cc < 8; ++cc) a[cc] = unpk(u[cc >> 1], cc & 1);
                #pragma unroll
                for (int oo = 0; oo < 64; ++oo) {
                    const float* wr = Wp + (size_t)(h * 64 + oo) * 128 + c0;
                    #pragma unroll
                    for (int cc = 0; cc < 8; ++cc) acc[oo] = fmaf(wr[cc], a[cc], acc[oo]);
                }
            }
            #pragma unroll
            for (int p2 = 0; p2 < 32; ++p2)
                yp[h * 32 + p2] = pack2(acc[2 * p2], acc[2 * p2 + 1]);
        }
        // LayerNorm stats over 128 (from packed y, self-consistent)
        float ps = 0.f, pq = 0.f;
        #pragma unroll
        for (int p2 = 0; p2 < 64; ++p2) {
            float a = unpk(yp[p2], 0), bb = unpk(yp[p2], 1);
            ps += a + bb;
            pq = fmaf(a, a, pq); pq = fmaf(bb, bb, pq);
        }
        float mean = ps * (1.f / 128.f);
        float var  = pq * (1.f / 128.f) - mean * mean;
        float rstd = rsqrtf(var + 1e-5f);
        size_t pixb = ((size_t)b * 128) * 65536
                    + (size_t)(2 * i0 + (px >> 1)) * 256 + (size_t)(2 * j + (px & 1));
        #pragma unroll
        for (int o = 0; o < 128; ++o) {
            float y  = unpk(yp[o >> 1], o & 1);
            float yn = (y - mean) * rstd * ln_g[o] + ln_b[o];
            size_t off = pixb + (size_t)o * 65536;
            out[sbase + off] = xhigh[off] + yn;
        }
    }
}

extern "C" void kernel_launch(void* const* d_in, const int* in_sizes, int n_in,
                              void* d_out, int out_size, void* d_ws, size_t ws_size,
                              hipStream_t stream) {
    const float* x_l   = (const float*)d_in[0];
    const float* x_r   = (const float*)d_in[1];
    const float* x_lh  = (const float*)d_in[2];
    const float* x_rh  = (const float*)d_in[3];
    const float* Wq    = (const float*)d_in[4];
    const float* bq    = (const float*)d_in[5];
    const float* Wqv   = (const float*)d_in[6];
    const float* bqv   = (const float*)d_in[7];
    const float* Wk    = (const float*)d_in[8];
    const float* bk    = (const float*)d_in[9];
    const float* Wv    = (const float*)d_in[10];
    const float* bv    = (const float*)d_in[11];
    const float* Wp    = (const float*)d_in[12];
    const float* bp    = (const float*)d_in[13];
    const float* ln_g  = (const float*)d_in[14];
    const float* ln_b  = (const float*)d_in[15];
    const float* dln1g = (const float*)d_in[16];
    const float* dln1b = (const float*)d_in[17];
    const float* d_wsv = (const float*)d_in[18];
    const float* d_w1  = (const float*)d_in[19];
    const float* dln2g = (const float*)d_in[20];
    const float* dln2b = (const float*)d_in[21];
    const float* d_w2  = (const float*)d_in[22];

    float* out = (float*)d_out;
    float* ws_mean = (float*)d_ws;            // 2048 floats
    float* ws_cm   = ws_mean + 2048;          // 1024 floats

    mean_kernel<<<2048, 256, 0, stream>>>(x_l, x_r, ws_mean);
    cm_kernel<<<8, 128, 0, stream>>>(ws_mean, ws_cm, Wk, bk, d_w1, dln2g, dln2b, d_w2);
    pafm_patch<<<512, 256, 0, stream>>>(x_l, x_r, x_lh, x_rh,
                                        Wq, bq, Wqv, bqv, Wk, bk, Wv, bv, Wp, bp,
                                        ln_g, ln_b, dln1g, dln1b, d_wsv, ws_cm, out);
}

// Round 9
// 3045.510 us; speedup vs baseline: 6.8847x; 1.2972x over previous
//
#include <hip/hip_runtime.h>
#include <hip/hip_bf16.h>
#include <math.h>

// PAFM fused v3: MFMA (16x16x32 bf16) for K/V/Q/VQ/P GEMMs.
// Inputs fp32 dict order; output fp32. B=4, DIM=128, CH=256, H=W=256, H0=W0=128,
// NH=8, HD=16, RD=8. Block = 64 patches (fixed i0, 64 consecutive j), 4 waves.

typedef short short8 __attribute__((ext_vector_type(8)));
typedef float f32x4 __attribute__((ext_vector_type(4)));

__device__ __forceinline__ unsigned bf16r(float x) {
    unsigned u = __float_as_uint(x);
    return (u + 0x7FFFu + ((u >> 16) & 1u)) >> 16;
}
__device__ __forceinline__ unsigned pack2(float a, float b) {
    return bf16r(a) | (bf16r(b) << 16);
}
__device__ __forceinline__ float ubf(unsigned short h) {
    return __uint_as_float(((unsigned)h) << 16);
}

// ---------------- kernel 1: per-(side,b,channel) spatial mean of x_low ----------------
__global__ __launch_bounds__(256) void mean_kernel(const float* __restrict__ x_l,
                                                   const float* __restrict__ x_r,
                                                   float* __restrict__ ws_mean) {
    int bid = blockIdx.x;                       // s*1024 + b*256 + c
    const float* src = (bid >= 1024) ? x_r : x_l;
    const float* p = src + (size_t)(bid & 1023) * 16384;
    int t = threadIdx.x;
    float acc = 0.f;
    #pragma unroll 4
    for (int i = t; i < 16384; i += 256) acc += p[i];
    #pragma unroll
    for (int off = 32; off > 0; off >>= 1) acc += __shfl_down(acc, off, 64);
    __shared__ float red[4];
    if ((t & 63) == 0) red[t >> 6] = acc;
    __syncthreads();
    if (t == 0) ws_mean[bid] = (red[0] + red[1] + red[2] + red[3]) * (1.f / 16384.f);
}

// ---------------- kernel 2: channel gate cm[side][b][128] ----------------
__global__ __launch_bounds__(128) void cm_kernel(const float* __restrict__ ws_mean,
                                                 float* __restrict__ ws_cm,
                                                 const float* __restrict__ Wk,
                                                 const float* __restrict__ bk,
                                                 const float* __restrict__ d_w1,
                                                 const float* __restrict__ d_ln2_g,
                                                 const float* __restrict__ d_ln2_b,
                                                 const float* __restrict__ d_w2) {
    int sb = blockIdx.x;
    __shared__ float km[128];
    int o = threadIdx.x;
    const float* mu = ws_mean + sb * 256;
    float acc = bk[o];
    for (int c = 0; c < 256; ++c) acc = fmaf(Wk[o * 256 + c], mu[c], acc);
    km[o] = acc;
    __syncthreads();
    int h = o >> 4, d = o & 15;
    float t1[8];
    #pragma unroll
    for (int r = 0; r < 8; ++r) {
        float a = 0.f;
        #pragma unroll
        for (int dd = 0; dd < 16; ++dd) a = fmaf(d_w1[r * 16 + dd], km[h * 16 + dd], a);
        t1[r] = a / (1.f + expf(-a));
    }
    float m = 0.f;
    #pragma unroll
    for (int r = 0; r < 8; ++r) m += t1[r];
    m *= 0.125f;
    float v = 0.f;
    #pragma unroll
    for (int r = 0; r < 8; ++r) { float df = t1[r] - m; v = fmaf(df, df, v); }
    float rstd = rsqrtf(v * 0.125f + 1e-5f);
    float cmv = 0.f;
    #pragma unroll
    for (int r = 0; r < 8; ++r)
        cmv = fmaf((t1[r] - m) * rstd * d_ln2_g[r] + d_ln2_b[r], d_w2[d * 8 + r], cmv);
    ws_cm[sb * 128 + o] = cmv;
}

// LDS offsets in u16 units
#define O_AB 0          // 16384 u16: A tiles (tgt 64x256 / Apx,xc,yn 128x128)
#define O_WB 16384      // 8192  u16: weight stage (Wk/Wv quarter 32x256; Wq/Wqv/Wp half 64x128)
#define O_KV 24576      // 8192  u16: k_s then v_s [64][128]
#define O_LG 32768      // 2048  u16: logits/aw [256 rows][8 heads]
#define O_SM 34816      // 1024 u16 = 512 f32: sm [64][8]
#define LDS_U16 35840

// stage activations: lanes along rows (coalesced); rows R, cols C2 (bf16), col pairs
__device__ __forceinline__ void stage_act(const float* __restrict__ g, size_t cstride,
                                          unsigned short* lds, int off, int R, int C2, int t) {
    int iters = (R * (C2 >> 1)) >> 8;
    for (int it = 0; it < iters; ++it) {
        int idx = t + (it << 8);
        int rr = idx & (R - 1);
        int cp = idx / R;
        float a0 = g[(size_t)(2 * cp) * cstride + rr];
        float a1 = g[(size_t)(2 * cp + 1) * cstride + rr];
        int col = (2 * cp) ^ ((rr & 7) << 3);
        *(unsigned*)&lds[off + rr * C2 + col] = pack2(a0, a1);
    }
}

// stage weights: row-major W[R][C2] fp32 -> bf16 swizzled
__device__ __forceinline__ void stage_w(const float* __restrict__ wsrc,
                                        unsigned short* lds, int off, int R, int C2, int t) {
    int cpairs = C2 >> 1;
    int iters = (R * cpairs) >> 8;
    for (int it = 0; it < iters; ++it) {
        int idx = t + (it << 8);
        int op = idx / cpairs;
        int cp = idx - op * cpairs;
        float a0 = wsrc[op * C2 + 2 * cp];
        float a1 = wsrc[op * C2 + 2 * cp + 1];
        int col = (2 * cp) ^ ((op & 7) << 3);
        *(unsigned*)&lds[off + op * C2 + col] = pack2(a0, a1);
    }
}

__device__ __forceinline__ short8 frag(const unsigned short* lds, int off, int row, int k, int C2) {
    return *(const short8*)&lds[off + row * C2 + (k ^ ((row & 7) << 3))];
}

// ---------------- kernel 3: fused main, MFMA ----------------
__global__ __launch_bounds__(256, 2) void pafm_mfma(
    const float* __restrict__ x_l,  const float* __restrict__ x_r,
    const float* __restrict__ x_lh, const float* __restrict__ x_rh,
    const float* __restrict__ Wq,   const float* __restrict__ bq,
    const float* __restrict__ Wqv,  const float* __restrict__ bqv,
    const float* __restrict__ Wk,   const float* __restrict__ bk,
    const float* __restrict__ Wv,   const float* __restrict__ bv,
    const float* __restrict__ Wp,   const float* __restrict__ bp,
    const float* __restrict__ ln_g, const float* __restrict__ ln_b,
    const float* __restrict__ d_ln1_g, const float* __restrict__ d_ln1_b,
    const float* __restrict__ d_wsv,
    const float* __restrict__ ws_cm,
    float* __restrict__ out) {

    __shared__ unsigned short lds[LDS_U16];
    float* smf = (float*)&lds[O_SM];

    int bid = blockIdx.x;                 // 2048 = s(1)|b(2)|i0(7)|jb(1)
    int s  = bid >> 10;
    int b  = (bid >> 8) & 3;
    int i0 = (bid >> 1) & 127;
    int j0 = (bid & 1) * 64;

    int t = threadIdx.x, w = t >> 6, l = t & 63, lm = l & 15, lg = l >> 4;

    const float* xlow  = s ? x_r  : x_l;
    const float* xhigh = s ? x_rh : x_lh;
    const float* cmp   = ws_cm + (s * 4 + b) * 128;

    // DANE per-d constants (d = lm)
    float gw = d_ln1_g[lm] * d_wsv[lm];
    float S1 = gw, S2 = d_ln1_b[lm] * d_wsv[lm];
    #pragma unroll
    for (int d = 1; d < 16; d <<= 1) { S1 += __shfl_xor(S1, d, 64); S2 += __shfl_xor(S2, d, 64); }

    const float* lowb = xlow + ((size_t)(b * 256) * 128 + i0) * 128 + j0;    // + c*16384 + jj

    // zero sm
    for (int i = t; i < 512; i += 256) smf[i] = 0.f;

    // ---- stage tgt + K GEMM (quarters) -> k_s ----
    stage_act(lowb, 16384, lds, O_AB, 64, 256, t);
    __syncthreads();
    #pragma unroll
    for (int h = 0; h < 4; ++h) {
        stage_w(Wk + (size_t)(32 * h) * 256, lds, O_WB, 32, 256, t);
        __syncthreads();
        f32x4 acck[2];
        acck[0] = (f32x4){0.f,0.f,0.f,0.f}; acck[1] = (f32x4){0.f,0.f,0.f,0.f};
        #pragma unroll
        for (int kc = 0; kc < 8; ++kc) {
            short8 af = frag(lds, O_AB, 16 * w + lm, kc * 32 + lg * 8, 256);
            #pragma unroll
            for (int ntl = 0; ntl < 2; ++ntl) {
                short8 bf = frag(lds, O_WB, 16 * ntl + lm, kc * 32 + lg * 8, 256);
                acck[ntl] = __builtin_amdgcn_mfma_f32_16x16x32_bf16(af, bf, acck[ntl], 0, 0, 0);
            }
        }
        __syncthreads();
        #pragma unroll
        for (int ntl = 0; ntl < 2; ++ntl) {
            int o = 32 * h + 16 * ntl + lm;
            float bias = bk[o];
            #pragma unroll
            for (int r = 0; r < 4; ++r) {
                int tok = 16 * w + 4 * lg + r;
                lds[O_KV + tok * 128 + (o ^ ((tok & 7) << 3))] = (unsigned short)bf16r(acck[ntl][r] + bias);
            }
        }
    }
    __syncthreads();

    // ---- pass 1: Q GEMM + logits + DANE (per dy) ----
    #pragma unroll
    for (int dy = 0; dy < 2; ++dy) {
        const float* hb = xhigh + ((size_t)(b * 128) * 256 + (2 * i0 + dy)) * 256 + 2 * j0;
        __syncthreads();
        stage_act(hb, 65536, lds, O_AB, 128, 128, t);
        __syncthreads();
        f32x4 accq[2][8];
        #pragma unroll
        for (int nh = 0; nh < 2; ++nh) {
            stage_w(Wq + (size_t)(64 * nh) * 128, lds, O_WB, 64, 128, t);
            __syncthreads();
            #pragma unroll
            for (int mt2 = 0; mt2 < 2; ++mt2)
                #pragma unroll
                for (int ntl = 0; ntl < 4; ++ntl)
                    accq[mt2][nh * 4 + ntl] = (f32x4){0.f,0.f,0.f,0.f};
            #pragma unroll
            for (int kc = 0; kc < 4; ++kc) {
                #pragma unroll
                for (int mt2 = 0; mt2 < 2; ++mt2) {
                    short8 af = frag(lds, O_AB, 32 * w + 16 * mt2 + lm, kc * 32 + lg * 8, 128);
                    #pragma unroll
                    for (int ntl = 0; ntl < 4; ++ntl) {
                        short8 bf = frag(lds, O_WB, 16 * ntl + lm, kc * 32 + lg * 8, 128);
                        accq[mt2][nh * 4 + ntl] =
                            __builtin_amdgcn_mfma_f32_16x16x32_bf16(af, bf, accq[mt2][nh * 4 + ntl], 0, 0, 0);
                    }
                }
            }
            __syncthreads();
        }
        // logits + DANE reduces
        #pragma unroll
        for (int mt2 = 0; mt2 < 2; ++mt2) {
            #pragma unroll
            for (int nt = 0; nt < 8; ++nt) {
                int o = 16 * nt + lm;
                float bias = bq[o];
                float sd2[2] = {0.f, 0.f};
                #pragma unroll
                for (int r = 0; r < 4; ++r) {
                    int row = 32 * w + 16 * mt2 + 4 * lg + r;
                    int tok = row >> 1;
                    float q = accq[mt2][nt][r] + bias;
                    float kv = ubf(lds[O_KV + tok * 128 + (o ^ ((tok & 7) << 3))]);
                    float t0 = q, t1 = q * q, t2 = q * gw, t3 = q * kv;
                    #pragma unroll
                    for (int d = 1; d < 16; d <<= 1) {
                        t0 += __shfl_xor(t0, d, 64); t1 += __shfl_xor(t1, d, 64);
                        t2 += __shfl_xor(t2, d, 64); t3 += __shfl_xor(t3, d, 64);
                    }
                    float mn = t0 * 0.0625f;
                    float var = t1 * 0.0625f - mn * mn;
                    float rs = rsqrtf(var + 1e-5f);
                    sd2[r >> 1] += rs * (t2 - mn * S1) + S2;
                    if (lm == 4 * mt2 + r)
                        lds[O_LG + (dy * 128 + row) * 8 + nt] = (unsigned short)bf16r(t3 * 0.25f);
                }
                #pragma unroll
                for (int pr = 0; pr < 2; ++pr)
                    if (lm == 2 * mt2 + pr) {
                        int jj = 16 * w + 8 * mt2 + 2 * lg + pr;
                        smf[jj * 8 + nt] += sd2[pr];
                    }
            }
        }
        __syncthreads();
    }

    // ---- softmax over 4 px + finalize sm ----
    #pragma unroll
    for (int ii = 0; ii < 2; ++ii) {
        int item = t + 256 * ii;          // 0..511
        int jj = item >> 3, h = item & 7;
        int r00 = (2 * jj) * 8 + h,       r01 = (2 * jj + 1) * 8 + h;
        int r10 = (128 + 2 * jj) * 8 + h, r11 = (128 + 2 * jj + 1) * 8 + h;
        float l00 = ubf(lds[O_LG + r00]), l01 = ubf(lds[O_LG + r01]);
        float l10 = ubf(lds[O_LG + r10]), l11 = ubf(lds[O_LG + r11]);
        float mx = fmaxf(fmaxf(l00, l01), fmaxf(l10, l11));
        float e00 = __expf(l00 - mx), e01 = __expf(l01 - mx);
        float e10 = __expf(l10 - mx), e11 = __expf(l11 - mx);
        float inv = 1.f / (e00 + e01 + e10 + e11);
        lds[O_LG + r00] = (unsigned short)bf16r(e00 * inv);
        lds[O_LG + r01] = (unsigned short)bf16r(e01 * inv);
        lds[O_LG + r10] = (unsigned short)bf16r(e10 * inv);
        lds[O_LG + r11] = (unsigned short)bf16r(e11 * inv);
        smf[jj * 8 + h] *= 0.25f;
    }
    __syncthreads();

    // ---- re-stage tgt + V GEMM (quarters) -> v_s (reuses KV region) ----
    stage_act(lowb, 16384, lds, O_AB, 64, 256, t);
    __syncthreads();
    #pragma unroll
    for (int h = 0; h < 4; ++h) {
        stage_w(Wv + (size_t)(32 * h) * 256, lds, O_WB, 32, 256, t);
        __syncthreads();
        f32x4 accv[2];
        accv[0] = (f32x4){0.f,0.f,0.f,0.f}; accv[1] = (f32x4){0.f,0.f,0.f,0.f};
        #pragma unroll
        for (int kc = 0; kc < 8; ++kc) {
            short8 af = frag(lds, O_AB, 16 * w + lm, kc * 32 + lg * 8, 256);
            #pragma unroll
            for (int ntl = 0; ntl < 2; ++ntl) {
                short8 bf = frag(lds, O_WB, 16 * ntl + lm, kc * 32 + lg * 8, 256);
                accv[ntl] = __builtin_amdgcn_mfma_f32_16x16x32_bf16(af, bf, accv[ntl], 0, 0, 0);
            }
        }
        __syncthreads();
        #pragma unroll
        for (int ntl = 0; ntl < 2; ++ntl) {
            int o = 32 * h + 16 * ntl + lm;
            float bias = bv[o];
            #pragma unroll
            for (int r = 0; r < 4; ++r) {
                int tok = 16 * w + 4 * lg + r;
                lds[O_KV + tok * 128 + (o ^ ((tok & 7) << 3))] = (unsigned short)bf16r(accv[ntl][r] + bias);
            }
        }
    }

    // ---- pass 2: VQ GEMM -> combine -> P GEMM -> LN -> store (per dy) ----
    #pragma unroll
    for (int dy = 0; dy < 2; ++dy) {
        const float* hb = xhigh + ((size_t)(b * 128) * 256 + (2 * i0 + dy)) * 256 + 2 * j0;
        __syncthreads();
        stage_act(hb, 65536, lds, O_AB, 128, 128, t);
        __syncthreads();
        f32x4 acc2[2][8];
        #pragma unroll
        for (int nh = 0; nh < 2; ++nh) {
            stage_w(Wqv + (size_t)(64 * nh) * 128, lds, O_WB, 64, 128, t);
            __syncthreads();
            #pragma unroll
            for (int mt2 = 0; mt2 < 2; ++mt2)
                #pragma unroll
                for (int ntl = 0; ntl < 4; ++ntl)
                    acc2[mt2][nh * 4 + ntl] = (f32x4){0.f,0.f,0.f,0.f};
            #pragma unroll
            for (int kc = 0; kc < 4; ++kc) {
                #pragma unroll
                for (int mt2 = 0; mt2 < 2; ++mt2) {
                    short8 af = frag(lds, O_AB, 32 * w + 16 * mt2 + lm, kc * 32 + lg * 8, 128);
                    #pragma unroll
                    for (int ntl = 0; ntl < 4; ++ntl) {
                        short8 bf = frag(lds, O_WB, 16 * ntl + lm, kc * 32 + lg * 8, 128);
                        acc2[mt2][nh * 4 + ntl] =
                            __builtin_amdgcn_mfma_f32_16x16x32_bf16(af, bf, acc2[mt2][nh * 4 + ntl], 0, 0, 0);
                    }
                }
            }
            __syncthreads();
        }
        // gate combine -> xc (overwrite AB; all VQ reads done)
        #pragma unroll
        for (int mt2 = 0; mt2 < 2; ++mt2) {
            #pragma unroll
            for (int nt = 0; nt < 8; ++nt) {
                int o = 16 * nt + lm;
                float bias = bqv[o];
                float cmv = cmp[o];
                #pragma unroll
                for (int r = 0; r < 4; ++r) {
                    int row = 32 * w + 16 * mt2 + 4 * lg + r;
                    int jj = row >> 1;
                    float vq = acc2[mt2][nt][r] + bias;
                    float aw = ubf(lds[O_LG + (dy * 128 + row) * 8 + nt]);
                    float vv = ubf(lds[O_KV + jj * 128 + (o ^ ((jj & 7) << 3))]);
                    float wg = 1.f / (1.f + __expf(-(smf[jj * 8 + nt] + cmv)));
                    float xc = (1.f - wg) * aw * vv * 4.f + wg * vq;
                    lds[O_AB + row * 128 + (o ^ ((row & 7) << 3))] = (unsigned short)bf16r(xc);
                }
            }
        }
        __syncthreads();
        // P GEMM
        f32x4 accy[2][8];
        #pragma unroll
        for (int nh = 0; nh < 2; ++nh) {
            stage_w(Wp + (size_t)(64 * nh) * 128, lds, O_WB, 64, 128, t);
            __syncthreads();
            #pragma unroll
            for (int mt2 = 0; mt2 < 2; ++mt2)
                #pragma unroll
                for (int ntl = 0; ntl < 4; ++ntl)
                    accy[mt2][nh * 4 + ntl] = (f32x4){0.f,0.f,0.f,0.f};
            #pragma unroll
            for (int kc = 0; kc < 4; ++kc) {
                #pragma unroll
                for (int mt2 = 0; mt2 < 2; ++mt2) {
                    short8 af = frag(lds, O_AB, 32 * w + 16 * mt2 + lm, kc * 32 + lg * 8, 128);
                    #pragma unroll
                    for (int ntl = 0; ntl < 4; ++ntl) {
                        short8 bf = frag(lds, O_WB, 16 * ntl + lm, kc * 32 + lg * 8, 128);
                        accy[mt2][nh * 4 + ntl] =
                            __builtin_amdgcn_mfma_f32_16x16x32_bf16(af, bf, accy[mt2][nh * 4 + ntl], 0, 0, 0);
                    }
                }
            }
            __syncthreads();
        }
        // LayerNorm stats per row + yn -> AB (yn swizzle), then store
        float mean_[2][4], rstd_[2][4];
        #pragma unroll
        for (int mt2 = 0; mt2 < 2; ++mt2) {
            #pragma unroll
            for (int r = 0; r < 4; ++r) {
                float ps = 0.f, pq = 0.f;
                #pragma unroll
                for (int nt = 0; nt < 8; ++nt) {
                    float y = accy[mt2][nt][r] + bp[16 * nt + lm];
                    ps += y; pq = fmaf(y, y, pq);
                }
                #pragma unroll
                for (int d = 1; d < 16; d <<= 1) {
                    ps += __shfl_xor(ps, d, 64); pq += __shfl_xor(pq, d, 64);
                }
                float mn = ps * (1.f / 128.f);
                float var = pq * (1.f / 128.f) - mn * mn;
                mean_[mt2][r] = mn;
                rstd_[mt2][r] = rsqrtf(var + 1e-5f);
            }
        }
        #pragma unroll
        for (int mt2 = 0; mt2 < 2; ++mt2) {
            #pragma unroll
            for (int nt = 0; nt < 8; ++nt) {
                int o = 16 * nt + lm;
                float gg = ln_g[o], bb2 = ln_b[o], bias = bp[o];
                #pragma unroll
                for (int r = 0; r < 4; ++r) {
                    int row = 32 * w + 16 * mt2 + 4 * lg + r;
                    float y = accy[mt2][nt][r] + bias;
                    float yn = (y - mean_[mt2][r]) * rstd_[mt2][r] * gg + bb2;
                    lds[O_AB + row * 128 + (o ^ ((row & 31) << 2))] = (unsigned short)bf16r(yn);
                }
            }
        }
        __syncthreads();
        // coalesced store + residual
        {
            const float* rb = hb;                       // xhigh, +c*65536 + ph
            float* ob = out + (size_t)s * 33554432
                      + ((size_t)(b * 128) * 256 + (2 * i0 + dy)) * 256 + 2 * j0;
            int ph = t & 127;
            int ohalf = t >> 7;
            for (int it = 0; it < 64; ++it) {
                int oo = 2 * it + ohalf;
                float yn = ubf(lds[O_AB + ph * 128 + (oo ^ ((ph & 31) << 2))]);
                size_t off = (size_t)oo * 65536 + ph;
                ob[off] = rb[off] + yn;
            }
        }
    }
}

extern "C" void kernel_launch(void* const* d_in, const int* in_sizes, int n_in,
                              void* d_out, int out_size, void* d_ws, size_t ws_size,
                              hipStream_t stream) {
    const float* x_l   = (const float*)d_in[0];
    const float* x_r   = (const float*)d_in[1];
    const float* x_lh  = (const float*)d_in[2];
    const float* x_rh  = (const float*)d_in[3];
    const float* Wq    = (const float*)d_in[4];
    const float* bq    = (const float*)d_in[5];
    const float* Wqv   = (const float*)d_in[6];
    const float* bqv   = (const float*)d_in[7];
    const float* Wk    = (const float*)d_in[8];
    const float* bk    = (const float*)d_in[9];
    const float* Wv    = (const float*)d_in[10];
    const float* bv    = (const float*)d_in[11];
    const float* Wp    = (const float*)d_in[12];
    const float* bp    = (const float*)d_in[13];
    const float* ln_g  = (const float*)d_in[14];
    const float* ln_b  = (const float*)d_in[15];
    const float* dln1g = (const float*)d_in[16];
    const float* dln1b = (const float*)d_in[17];
    const float* d_wsv = (const float*)d_in[18];
    const float* d_w1  = (const float*)d_in[19];
    const float* dln2g = (const float*)d_in[20];
    const float* dln2b = (const float*)d_in[21];
    const float* d_w2  = (const float*)d_in[22];

    float* out = (float*)d_out;
    float* ws_mean = (float*)d_ws;            // 2048 floats
    float* ws_cm   = ws_mean + 2048;          // 1024 floats

    mean_kernel<<<2048, 256, 0, stream>>>(x_l, x_r, ws_mean);
    cm_kernel<<<8, 128, 0, stream>>>(ws_mean, ws_cm, Wk, bk, d_w1, dln2g, dln2b, d_w2);
    pafm_mfma<<<2048, 256, 0, stream>>>(x_l, x_r, x_lh, x_rh,
                                        Wq, bq, Wqv, bqv, Wk, bk, Wv, bv, Wp, bp,
                                        ln_g, ln_b, dln1g, dln1b, d_wsv, ws_cm, out);
}

// Round 10
// 2633.182 us; speedup vs baseline: 7.9628x; 1.1566x over previous
//
#include <hip/hip_runtime.h>
#include <hip/hip_bf16.h>
#include <math.h>

// PAFM fused v4: MFMA with scratch-proof accumulators (named arrays, only
// literal-index loops; barrier-containing levels manually duplicated).
// Inputs fp32 dict order; output fp32. B=4, DIM=128, CH=256, H=W=256, H0=W0=128.
// Block = 64 patches (fixed i0, 64 j), 4 waves, grid 2048.

typedef short short8 __attribute__((ext_vector_type(8)));
typedef float f32x4 __attribute__((ext_vector_type(4)));

__device__ __forceinline__ unsigned bf16r(float x) {
    unsigned u = __float_as_uint(x);
    return (u + 0x7FFFu + ((u >> 16) & 1u)) >> 16;
}
__device__ __forceinline__ unsigned pack2(float a, float b) {
    return bf16r(a) | (bf16r(b) << 16);
}
__device__ __forceinline__ float ubf(unsigned short h) {
    return __uint_as_float(((unsigned)h) << 16);
}

// ---------------- kernel 1: per-(side,b,channel) spatial mean of x_low ----------------
__global__ __launch_bounds__(256) void mean_kernel(const float* __restrict__ x_l,
                                                   const float* __restrict__ x_r,
                                                   float* __restrict__ ws_mean) {
    int bid = blockIdx.x;
    const float* src = (bid >= 1024) ? x_r : x_l;
    const float* p = src + (size_t)(bid & 1023) * 16384;
    int t = threadIdx.x;
    float acc = 0.f;
    #pragma unroll 4
    for (int i = t; i < 16384; i += 256) acc += p[i];
    #pragma unroll
    for (int off = 32; off > 0; off >>= 1) acc += __shfl_down(acc, off, 64);
    __shared__ float red[4];
    if ((t & 63) == 0) red[t >> 6] = acc;
    __syncthreads();
    if (t == 0) ws_mean[bid] = (red[0] + red[1] + red[2] + red[3]) * (1.f / 16384.f);
}

// ---------------- kernel 2: channel gate cm[side][b][128] ----------------
__global__ __launch_bounds__(128) void cm_kernel(const float* __restrict__ ws_mean,
                                                 float* __restrict__ ws_cm,
                                                 const float* __restrict__ Wk,
                                                 const float* __restrict__ bk,
                                                 const float* __restrict__ d_w1,
                                                 const float* __restrict__ d_ln2_g,
                                                 const float* __restrict__ d_ln2_b,
                                                 const float* __restrict__ d_w2) {
    int sb = blockIdx.x;
    __shared__ float km[128];
    int o = threadIdx.x;
    const float* mu = ws_mean + sb * 256;
    float acc = bk[o];
    for (int c = 0; c < 256; ++c) acc = fmaf(Wk[o * 256 + c], mu[c], acc);
    km[o] = acc;
    __syncthreads();
    int h = o >> 4, d = o & 15;
    float t1[8];
    #pragma unroll
    for (int r = 0; r < 8; ++r) {
        float a = 0.f;
        #pragma unroll
        for (int dd = 0; dd < 16; ++dd) a = fmaf(d_w1[r * 16 + dd], km[h * 16 + dd], a);
        t1[r] = a / (1.f + expf(-a));
    }
    float m = 0.f;
    #pragma unroll
    for (int r = 0; r < 8; ++r) m += t1[r];
    m *= 0.125f;
    float v = 0.f;
    #pragma unroll
    for (int r = 0; r < 8; ++r) { float df = t1[r] - m; v = fmaf(df, df, v); }
    float rstd = rsqrtf(v * 0.125f + 1e-5f);
    float cmv = 0.f;
    #pragma unroll
    for (int r = 0; r < 8; ++r)
        cmv = fmaf((t1[r] - m) * rstd * d_ln2_g[r] + d_ln2_b[r], d_w2[d * 8 + r], cmv);
    ws_cm[sb * 128 + o] = cmv;
}

// LDS offsets in u16 units
#define O_AB 0          // 16384 u16
#define O_WB 16384      // 8192  u16
#define O_KV 24576      // 8192  u16: k_s then v_s [64][128]
#define O_LG 32768      // 2048  u16: logits/aw [256 rows][8 heads]
#define O_SM 34816      // 1024 u16 = 512 f32
#define LDS_U16 35840

__device__ __forceinline__ void stage_act(const float* __restrict__ g, size_t cstride,
                                          unsigned short* lds, int off, int R, int C2, int t) {
    int iters = (R * (C2 >> 1)) >> 8;
    for (int it = 0; it < iters; ++it) {
        int idx = t + (it << 8);
        int rr = idx & (R - 1);
        int cp = idx / R;
        float a0 = g[(size_t)(2 * cp) * cstride + rr];
        float a1 = g[(size_t)(2 * cp + 1) * cstride + rr];
        int col = (2 * cp) ^ ((rr & 7) << 3);
        *(unsigned*)&lds[off + rr * C2 + col] = pack2(a0, a1);
    }
}

__device__ __forceinline__ void stage_w(const float* __restrict__ wsrc,
                                        unsigned short* lds, int off, int R, int C2, int t) {
    int cpairs = C2 >> 1;
    int iters = (R * cpairs) >> 8;
    for (int it = 0; it < iters; ++it) {
        int idx = t + (it << 8);
        int op = idx / cpairs;
        int cp = idx - op * cpairs;
        float a0 = wsrc[op * C2 + 2 * cp];
        float a1 = wsrc[op * C2 + 2 * cp + 1];
        int col = (2 * cp) ^ ((op & 7) << 3);
        *(unsigned*)&lds[off + op * C2 + col] = pack2(a0, a1);
    }
}

__device__ __forceinline__ short8 frag(const unsigned short* lds, int off, int row, int k, int C2) {
    return *(const short8*)&lds[off + row * C2 + (k ^ ((row & 7) << 3))];
}

// ---- macros: all acc indices come only from tiny barrier-free unrolled loops ----
#define MFMA_HALF_128(ACC, WSRC) do {                                              \
    __syncthreads();                                                               \
    stage_w((WSRC), lds, O_WB, 64, 128, t);                                        \
    __syncthreads();                                                               \
    _Pragma("unroll")                                                              \
    for (int mt2_ = 0; mt2_ < 2; ++mt2_)                                           \
      _Pragma("unroll")                                                            \
      for (int ntl_ = 0; ntl_ < 4; ++ntl_) ACC[mt2_][ntl_] = (f32x4){0.f,0.f,0.f,0.f}; \
    _Pragma("unroll")                                                              \
    for (int kc_ = 0; kc_ < 4; ++kc_) {                                            \
      _Pragma("unroll")                                                            \
      for (int mt2_ = 0; mt2_ < 2; ++mt2_) {                                       \
        short8 af_ = frag(lds, O_AB, 32 * w + 16 * mt2_ + lm, kc_ * 32 + lg * 8, 128); \
        _Pragma("unroll")                                                          \
        for (int ntl_ = 0; ntl_ < 4; ++ntl_) {                                     \
          short8 bf_ = frag(lds, O_WB, 16 * ntl_ + lm, kc_ * 32 + lg * 8, 128);    \
          ACC[mt2_][ntl_] = __builtin_amdgcn_mfma_f32_16x16x32_bf16(af_, bf_, ACC[mt2_][ntl_], 0, 0, 0); \
        }                                                                          \
      }                                                                            \
    }                                                                              \
  } while (0)

#define KV_QUARTER(WSRC, BIAS, OBASE) do {                                         \
    __syncthreads();                                                               \
    stage_w((WSRC), lds, O_WB, 32, 256, t);                                        \
    __syncthreads();                                                               \
    f32x4 a0_ = (f32x4){0.f,0.f,0.f,0.f}, a1_ = (f32x4){0.f,0.f,0.f,0.f};          \
    _Pragma("unroll")                                                              \
    for (int kc_ = 0; kc_ < 8; ++kc_) {                                            \
      short8 af_ = frag(lds, O_AB, 16 * w + lm, kc_ * 32 + lg * 8, 256);           \
      short8 b0_ = frag(lds, O_WB, lm, kc_ * 32 + lg * 8, 256);                    \
      a0_ = __builtin_amdgcn_mfma_f32_16x16x32_bf16(af_, b0_, a0_, 0, 0, 0);       \
      short8 b1_ = frag(lds, O_WB, 16 + lm, kc_ * 32 + lg * 8, 256);               \
      a1_ = __builtin_amdgcn_mfma_f32_16x16x32_bf16(af_, b1_, a1_, 0, 0, 0);       \
    }                                                                              \
    {                                                                              \
      int o0_ = (OBASE) + lm, o1_ = (OBASE) + 16 + lm;                             \
      float bb0_ = (BIAS)[o0_], bb1_ = (BIAS)[o1_];                                \
      _Pragma("unroll")                                                            \
      for (int r_ = 0; r_ < 4; ++r_) {                                             \
        int tok_ = 16 * w + 4 * lg + r_;                                           \
        lds[O_KV + tok_ * 128 + (o0_ ^ ((tok_ & 7) << 3))] = (unsigned short)bf16r(a0_[r_] + bb0_); \
        lds[O_KV + tok_ * 128 + (o1_ ^ ((tok_ & 7) << 3))] = (unsigned short)bf16r(a1_[r_] + bb1_); \
      }                                                                            \
    }                                                                              \
  } while (0)

#define CONSUME_Q(ACC, NH) do {                                                    \
    _Pragma("unroll")                                                              \
    for (int mt2_ = 0; mt2_ < 2; ++mt2_) {                                         \
      _Pragma("unroll")                                                            \
      for (int nt2_ = 0; nt2_ < 4; ++nt2_) {                                       \
        int nt_ = 4 * (NH) + nt2_;                                                 \
        int o_ = 16 * nt_ + lm;                                                    \
        float bias_ = bq[o_];                                                      \
        float sd0_ = 0.f, sd1_ = 0.f;                                              \
        _Pragma("unroll")                                                          \
        for (int r_ = 0; r_ < 4; ++r_) {                                           \
          int row_ = 32 * w + 16 * mt2_ + 4 * lg + r_;                             \
          int tok_ = row_ >> 1;                                                    \
          float q_ = ACC[mt2_][nt2_][r_] + bias_;                                  \
          float kv_ = ubf(lds[O_KV + tok_ * 128 + (o_ ^ ((tok_ & 7) << 3))]);      \
          float t0_ = q_, t1_ = q_ * q_, t2_ = q_ * gw, t3_ = q_ * kv_;            \
          _Pragma("unroll")                                                        \
          for (int d_ = 1; d_ < 16; d_ <<= 1) {                                    \
            t0_ += __shfl_xor(t0_, d_, 64); t1_ += __shfl_xor(t1_, d_, 64);        \
            t2_ += __shfl_xor(t2_, d_, 64); t3_ += __shfl_xor(t3_, d_, 64);        \
          }                                                                        \
          float mn_ = t0_ * 0.0625f;                                               \
          float var_ = t1_ * 0.0625f - mn_ * mn_;                                  \
          float rs_ = rsqrtf(var_ + 1e-5f);                                        \
          float sdt_ = rs_ * (t2_ - mn_ * S1) + S2;                                \
          if (r_ < 2) sd0_ += sdt_; else sd1_ += sdt_;                             \
          if (lm == 4 * mt2_ + r_)                                                 \
            lds[O_LG + (dy * 128 + row_) * 8 + nt_] = (unsigned short)bf16r(t3_ * 0.25f); \
        }                                                                          \
        if (lm == 2 * mt2_) { int jj_ = 16 * w + 8 * mt2_ + 2 * lg; smf[jj_ * 8 + nt_] += sd0_; } \
        if (lm == 2 * mt2_ + 1) { int jj_ = 16 * w + 8 * mt2_ + 2 * lg + 1; smf[jj_ * 8 + nt_] += sd1_; } \
      }                                                                            \
    }                                                                              \
  } while (0)

#define COMBINE(ACC, NH) do {                                                      \
    _Pragma("unroll")                                                              \
    for (int mt2_ = 0; mt2_ < 2; ++mt2_) {                                         \
      _Pragma("unroll")                                                            \
      for (int nt2_ = 0; nt2_ < 4; ++nt2_) {                                       \
        int nt_ = 4 * (NH) + nt2_;                                                 \
        int o_ = 16 * nt_ + lm;                                                    \
        float bias_ = bqv[o_];                                                     \
        float cmv_ = cmp[o_];                                                      \
        _Pragma("unroll")                                                          \
        for (int r_ = 0; r_ < 4; ++r_) {                                           \
          int row_ = 32 * w + 16 * mt2_ + 4 * lg + r_;                             \
          int jj_ = row_ >> 1;                                                     \
          float vq_ = ACC[mt2_][nt2_][r_] + bias_;                                 \
          float aw_ = ubf(lds[O_LG + (dy * 128 + row_) * 8 + nt_]);                \
          float vv_ = ubf(lds[O_KV + jj_ * 128 + (o_ ^ ((jj_ & 7) << 3))]);        \
          float wg_ = 1.f / (1.f + __expf(-(smf[jj_ * 8 + nt_] + cmv_)));          \
          float xc_ = (1.f - wg_) * aw_ * vv_ * 4.f + wg_ * vq_;                   \
          lds[O_AB + row_ * 128 + (o_ ^ ((row_ & 7) << 3))] = (unsigned short)bf16r(xc_); \
        }                                                                          \
      }                                                                            \
    }                                                                              \
  } while (0)

#define YN_WRITE(ACC, NH) do {                                                     \
    _Pragma("unroll")                                                              \
    for (int mt2_ = 0; mt2_ < 2; ++mt2_) {                                         \
      _Pragma("unroll")                                                            \
      for (int nt2_ = 0; nt2_ < 4; ++nt2_) {                                       \
        int o_ = 16 * (4 * (NH) + nt2_) + lm;                                      \
        float gg_ = ln_g[o_], bb_ = ln_b[o_], bias_ = bp[o_];                      \
        _Pragma("unroll")                                                          \
        for (int r_ = 0; r_ < 4; ++r_) {                                           \
          int row_ = 32 * w + 16 * mt2_ + 4 * lg + r_;                             \
          float y_ = ACC[mt2_][nt2_][r_] + bias_;                                  \
          float yn_ = (y_ - mean_[mt2_][r_]) * rstd_[mt2_][r_] * gg_ + bb_;        \
          lds[O_AB + row_ * 128 + (o_ ^ ((row_ & 31) << 2))] = (unsigned short)bf16r(yn_); \
        }                                                                          \
      }                                                                            \
    }                                                                              \
  } while (0)

// ---------------- kernel 3: fused main, MFMA ----------------
__global__ __launch_bounds__(256, 2) void pafm_mfma(
    const float* __restrict__ x_l,  const float* __restrict__ x_r,
    const float* __restrict__ x_lh, const float* __restrict__ x_rh,
    const float* __restrict__ Wq,   const float* __restrict__ bq,
    const float* __restrict__ Wqv,  const float* __restrict__ bqv,
    const float* __restrict__ Wk,   const float* __restrict__ bk,
    const float* __restrict__ Wv,   const float* __restrict__ bv,
    const float* __restrict__ Wp,   const float* __restrict__ bp,
    const float* __restrict__ ln_g, const float* __restrict__ ln_b,
    const float* __restrict__ d_ln1_g, const float* __restrict__ d_ln1_b,
    const float* __restrict__ d_wsv,
    const float* __restrict__ ws_cm,
    float* __restrict__ out) {

    __shared__ unsigned short lds[LDS_U16];
    float* smf = (float*)&lds[O_SM];

    int bid = blockIdx.x;
    int s  = bid >> 10;
    int b  = (bid >> 8) & 3;
    int i0 = (bid >> 1) & 127;
    int j0 = (bid & 1) * 64;

    int t = threadIdx.x, w = t >> 6, l = t & 63, lm = l & 15, lg = l >> 4;

    const float* xlow  = s ? x_r  : x_l;
    const float* xhigh = s ? x_rh : x_lh;
    const float* cmp   = ws_cm + (s * 4 + b) * 128;

    float gw = d_ln1_g[lm] * d_wsv[lm];
    float S1 = gw, S2 = d_ln1_b[lm] * d_wsv[lm];
    #pragma unroll
    for (int d = 1; d < 16; d <<= 1) { S1 += __shfl_xor(S1, d, 64); S2 += __shfl_xor(S2, d, 64); }

    const float* lowb = xlow + ((size_t)(b * 256) * 128 + i0) * 128 + j0;

    for (int i = t; i < 512; i += 256) smf[i] = 0.f;

    // ---- stage tgt + K GEMM quarters -> k_s ----
    stage_act(lowb, 16384, lds, O_AB, 64, 256, t);
    KV_QUARTER(Wk,             bk, 0);
    KV_QUARTER(Wk +  32 * 256, bk, 32);
    KV_QUARTER(Wk +  64 * 256, bk, 64);
    KV_QUARTER(Wk +  96 * 256, bk, 96);

    // ---- pass 1: Q GEMM + logits + DANE (per dy) ----
    for (int dy = 0; dy < 2; ++dy) {
        const float* hb = xhigh + ((size_t)(b * 128) * 256 + (2 * i0 + dy)) * 256 + 2 * j0;
        __syncthreads();
        stage_act(hb, 65536, lds, O_AB, 128, 128, t);
        f32x4 aqA[2][4], aqB[2][4];
        MFMA_HALF_128(aqA, Wq);
        MFMA_HALF_128(aqB, Wq + 64 * 128);
        CONSUME_Q(aqA, 0);
        CONSUME_Q(aqB, 1);
    }
    __syncthreads();

    // ---- softmax over 4 px + finalize sm ----
    #pragma unroll
    for (int ii = 0; ii < 2; ++ii) {
        int item = t + 256 * ii;
        int jj = item >> 3, h = item & 7;
        int r00 = (2 * jj) * 8 + h,       r01 = (2 * jj + 1) * 8 + h;
        int r10 = (128 + 2 * jj) * 8 + h, r11 = (128 + 2 * jj + 1) * 8 + h;
        float l00 = ubf(lds[O_LG + r00]), l01 = ubf(lds[O_LG + r01]);
        float l10 = ubf(lds[O_LG + r10]), l11 = ubf(lds[O_LG + r11]);
        float mx = fmaxf(fmaxf(l00, l01), fmaxf(l10, l11));
        float e00 = __expf(l00 - mx), e01 = __expf(l01 - mx);
        float e10 = __expf(l10 - mx), e11 = __expf(l11 - mx);
        float inv = 1.f / (e00 + e01 + e10 + e11);
        lds[O_LG + r00] = (unsigned short)bf16r(e00 * inv);
        lds[O_LG + r01] = (unsigned short)bf16r(e01 * inv);
        lds[O_LG + r10] = (unsigned short)bf16r(e10 * inv);
        lds[O_LG + r11] = (unsigned short)bf16r(e11 * inv);
        smf[jj * 8 + h] *= 0.25f;
    }
    __syncthreads();

    // ---- re-stage tgt + V GEMM quarters -> v_s ----
    stage_act(lowb, 16384, lds, O_AB, 64, 256, t);
    KV_QUARTER(Wv,             bv, 0);
    KV_QUARTER(Wv +  32 * 256, bv, 32);
    KV_QUARTER(Wv +  64 * 256, bv, 64);
    KV_QUARTER(Wv +  96 * 256, bv, 96);

    // ---- pass 2: VQ -> combine -> P -> LN -> store (per dy) ----
    for (int dy = 0; dy < 2; ++dy) {
        const float* hb = xhigh + ((size_t)(b * 128) * 256 + (2 * i0 + dy)) * 256 + 2 * j0;
        __syncthreads();
        stage_act(hb, 65536, lds, O_AB, 128, 128, t);
        f32x4 vqA[2][4], vqB[2][4];
        MFMA_HALF_128(vqA, Wqv);
        MFMA_HALF_128(vqB, Wqv + 64 * 128);
        __syncthreads();                 // all VQ reads of AB done
        COMBINE(vqA, 0);
        COMBINE(vqB, 1);
        f32x4 accyA[2][4], accyB[2][4];
        MFMA_HALF_128(accyA, Wp);        // leading sync orders combine writes
        MFMA_HALF_128(accyB, Wp + 64 * 128);
        __syncthreads();                 // all P reads of AB done
        // LayerNorm stats
        float mean_[2][4], rstd_[2][4];
        #pragma unroll
        for (int mt2 = 0; mt2 < 2; ++mt2) {
            #pragma unroll
            for (int r = 0; r < 4; ++r) {
                float ps = 0.f, pq = 0.f;
                #pragma unroll
                for (int nt2 = 0; nt2 < 4; ++nt2) {
                    float y = accyA[mt2][nt2][r] + bp[16 * nt2 + lm];
                    ps += y; pq = fmaf(y, y, pq);
                    float y2 = accyB[mt2][nt2][r] + bp[16 * (4 + nt2) + lm];
                    ps += y2; pq = fmaf(y2, y2, pq);
                }
                #pragma unroll
                for (int d = 1; d < 16; d <<= 1) { ps += __shfl_xor(ps, d, 64); pq += __shfl_xor(pq, d, 64); }
                float mn = ps * (1.f / 128.f);
                float var = pq * (1.f / 128.f) - mn * mn;
                mean_[mt2][r] = mn;
                rstd_[mt2][r] = rsqrtf(var + 1e-5f);
            }
        }
        YN_WRITE(accyA, 0);
        YN_WRITE(accyB, 1);
        __syncthreads();
        // coalesced store + residual
        {
            const float* rb = hb;
            float* ob = out + (size_t)s * 33554432
                      + ((size_t)(b * 128) * 256 + (2 * i0 + dy)) * 256 + 2 * j0;
            int ph = t & 127;
            int ohalf = t >> 7;
            #pragma unroll 8
            for (int it = 0; it < 64; ++it) {
                int oo = 2 * it + ohalf;
                float yn = ubf(lds[O_AB + ph * 128 + (oo ^ ((ph & 31) << 2))]);
                size_t off = (size_t)oo * 65536 + ph;
                ob[off] = rb[off] + yn;
            }
        }
    }
}

extern "C" void kernel_launch(void* const* d_in, const int* in_sizes, int n_in,
                              void* d_out, int out_size, void* d_ws, size_t ws_size,
                              hipStream_t stream) {
    const float* x_l   = (const float*)d_in[0];
    const float* x_r   = (const float*)d_in[1];
    const float* x_lh  = (const float*)d_in[2];
    const float* x_rh  = (const float*)d_in[3];
    const float* Wq    = (const float*)d_in[4];
    const float* bq    = (const float*)d_in[5];
    const float* Wqv   = (const float*)d_in[6];
    const float* bqv   = (const float*)d_in[7];
    const float* Wk    = (const float*)d_in[8];
    const float* bk    = (const float*)d_in[9];
    const float* Wv    = (const float*)d_in[10];
    const float* bv    = (const float*)d_in[11];
    const float* Wp    = (const float*)d_in[12];
    const float* bp    = (const float*)d_in[13];
    const float* ln_g  = (const float*)d_in[14];
    const float* ln_b  = (const float*)d_in[15];
    const float* dln1g = (const float*)d_in[16];
    const float* dln1b = (const float*)d_in[17];
    const float* d_wsv = (const float*)d_in[18];
    const float* d_w1  = (const float*)d_in[19];
    const float* dln2g = (const float*)d_in[20];
    const float* dln2b = (const float*)d_in[21];
    const float* d_w2  = (const float*)d_in[22];

    float* out = (float*)d_out;
    float* ws_mean = (float*)d_ws;
    float* ws_cm   = ws_mean + 2048;

    mean_kernel<<<2048, 256, 0, stream>>>(x_l, x_r, ws_mean);
    cm_kernel<<<8, 128, 0, stream>>>(ws_mean, ws_cm, Wk, bk, d_w1, dln2g, dln2b, d_w2);
    pafm_mfma<<<2048, 256, 0, stream>>>(x_l, x_r, x_lh, x_rh,
                                        Wq, bq, Wqv, bqv, Wk, bk, Wv, bv, Wp, bp,
                                        ln_g, ln_b, dln1g, dln1b, d_wsv, ws_cm, out);
}

// Round 11
// 610.706 us; speedup vs baseline: 34.3333x; 4.3117x over previous
//
#include <hip/hip_runtime.h>
#include <hip/hip_bf16.h>
#include <math.h>

// PAFM fused v5: 512-thr block / 64 patches, 150KB LDS, scratch-proof single-tile
// accs, bf16 pre-swizzled weights in ws. Inputs fp32 dict order; output fp32.
// B=4, DIM=128, CH=256, H=W=256, H0=W0=128, NH=8, HD=16, RD=8. Grid 2048.

typedef short short8 __attribute__((ext_vector_type(8)));
typedef float f32x4 __attribute__((ext_vector_type(4)));

__device__ __forceinline__ unsigned bf16r(float x) {
    unsigned u = __float_as_uint(x);
    return (u + 0x7FFFu + ((u >> 16) & 1u)) >> 16;
}
__device__ __forceinline__ unsigned pack2(float a, float b) {
    return bf16r(a) | (bf16r(b) << 16);
}
__device__ __forceinline__ float ubf(unsigned short h) {
    return __uint_as_float(((unsigned)h) << 16);
}

// ---------------- kernel 1: per-(side,b,channel) spatial mean of x_low ----------------
__global__ __launch_bounds__(256) void mean_kernel(const float* __restrict__ x_l,
                                                   const float* __restrict__ x_r,
                                                   float* __restrict__ ws_mean) {
    int bid = blockIdx.x;
    const float* src = (bid >= 1024) ? x_r : x_l;
    const float* p = src + (size_t)(bid & 1023) * 16384;
    int t = threadIdx.x;
    float acc = 0.f;
    #pragma unroll 4
    for (int i = t; i < 16384; i += 256) acc += p[i];
    #pragma unroll
    for (int off = 32; off > 0; off >>= 1) acc += __shfl_down(acc, off, 64);
    __shared__ float red[4];
    if ((t & 63) == 0) red[t >> 6] = acc;
    __syncthreads();
    if (t == 0) ws_mean[bid] = (red[0] + red[1] + red[2] + red[3]) * (1.f / 16384.f);
}

// ---------------- kernel 2: channel gate cm[side][b][128] ----------------
__global__ __launch_bounds__(128) void cm_kernel(const float* __restrict__ ws_mean,
                                                 float* __restrict__ ws_cm,
                                                 const float* __restrict__ Wk,
                                                 const float* __restrict__ bk,
                                                 const float* __restrict__ d_w1,
                                                 const float* __restrict__ d_ln2_g,
                                                 const float* __restrict__ d_ln2_b,
                                                 const float* __restrict__ d_w2) {
    int sb = blockIdx.x;
    __shared__ float km[128];
    int o = threadIdx.x;
    const float* mu = ws_mean + sb * 256;
    float acc = bk[o];
    for (int c = 0; c < 256; ++c) acc = fmaf(Wk[o * 256 + c], mu[c], acc);
    km[o] = acc;
    __syncthreads();
    int h = o >> 4, d = o & 15;
    float t1[8];
    #pragma unroll
    for (int r = 0; r < 8; ++r) {
        float a = 0.f;
        #pragma unroll
        for (int dd = 0; dd < 16; ++dd) a = fmaf(d_w1[r * 16 + dd], km[h * 16 + dd], a);
        t1[r] = a / (1.f + expf(-a));
    }
    float m = 0.f;
    #pragma unroll
    for (int r = 0; r < 8; ++r) m += t1[r];
    m *= 0.125f;
    float v = 0.f;
    #pragma unroll
    for (int r = 0; r < 8; ++r) { float df = t1[r] - m; v = fmaf(df, df, v); }
    float rstd = rsqrtf(v * 0.125f + 1e-5f);
    float cmv = 0.f;
    #pragma unroll
    for (int r = 0; r < 8; ++r)
        cmv = fmaf((t1[r] - m) * rstd * d_ln2_g[r] + d_ln2_b[r], d_w2[d * 8 + r], cmv);
    ws_cm[sb * 128 + o] = cmv;
}

// ---------------- kernel 2b: weights -> bf16 pre-swizzled pool in ws ----------------
// pool (u16): WKs=0 [4][32][256]; WVs=32768; WQs=65536 [2][64][128]; WQVs=81920; WPs=98304
__global__ __launch_bounds__(256) void wprep(const float* __restrict__ Wq,
                                             const float* __restrict__ Wqv,
                                             const float* __restrict__ Wk,
                                             const float* __restrict__ Wv,
                                             const float* __restrict__ Wp,
                                             unsigned short* __restrict__ wsp) {
    int bid = blockIdx.x, t = threadIdx.x;
    if (bid < 64) {                       // Wk (0-31) / Wv (32-63)
        const float* src = (bid < 32) ? Wk : Wv;
        unsigned short* dst = wsp + ((bid < 32) ? 0 : 32768);
        int base = (bid & 31) * 1024;
        #pragma unroll
        for (int i = 0; i < 4; ++i) {
            int el = base + t + 256 * i;
            int q = el >> 13, rem = el & 8191, op = rem >> 8, col = rem & 255;
            dst[q * 8192 + op * 256 + (col ^ ((op & 7) << 3))] =
                (unsigned short)bf16r(src[(q * 32 + op) * 256 + col]);
        }
    } else {                              // Wq (64-79) / Wqv (80-95) / Wp (96-111)
        int g = (bid - 64) >> 4;
        const float* src = (g == 0) ? Wq : (g == 1) ? Wqv : Wp;
        unsigned short* dst = wsp + 65536 + g * 16384;
        int base = ((bid - 64) & 15) * 1024;
        #pragma unroll
        for (int i = 0; i < 4; ++i) {
            int el = base + t + 256 * i;
            int hf = el >> 13, rem = el & 8191, op = rem >> 7, col = rem & 127;
            dst[hf * 8192 + op * 128 + (col ^ ((op & 7) << 3))] =
                (unsigned short)bf16r(src[(hf * 64 + op) * 128 + col]);
        }
    }
}

// LDS offsets (u16)
#define O_XH0 0
#define O_XH1 16384
#define O_XC  32768
#define O_WB  49152
#define O_K   57344
#define O_V   65536
#define O_LG  73728
#define O_SM  75776
#define LDS_U16 76800   // 150 KB

__device__ __forceinline__ short8 frag(const unsigned short* lds, int off, int row, int k, int C2) {
    return *(const short8*)&lds[off + row * C2 + (k ^ ((row & 7) << 3))];
}

template<int R, int C2>
__device__ __forceinline__ void stageA(const float* __restrict__ g, size_t cstride,
                                       unsigned short* lds, int off, int t) {
    #pragma unroll
    for (int it = 0; it < (R * (C2 / 2)) / 512; ++it) {
        int idx = t + it * 512;
        int rr = idx & (R - 1);
        int cp = idx / R;
        float a0 = g[(size_t)(2 * cp) * cstride + rr];
        float a1 = g[(size_t)(2 * cp + 1) * cstride + rr];
        int col = (2 * cp) ^ ((rr & 7) << 3);
        *(unsigned*)&lds[off + rr * C2 + col] = pack2(a0, a1);
    }
}

// linear 16KB copy of pre-swizzled bf16 weights
__device__ __forceinline__ void stageW16(const unsigned short* __restrict__ src,
                                         unsigned short* lds, int t) {
    #pragma unroll
    for (int c = 0; c < 2; ++c) {
        int u = (c * 512 + t) * 8;
        *(short8*)&lds[O_WB + u] = *(const short8*)&src[u];
    }
}

#define ZERO4(A) do { _Pragma("unroll") for (int z_ = 0; z_ < 4; ++z_) A[z_] = (f32x4){0.f,0.f,0.f,0.f}; } while (0)

#define KVQ(WOFF, BIAS, OBASE, ODST) do {                                          \
    stageW16(wsp + (WOFF), lds, t);                                                \
    __syncthreads();                                                               \
    f32x4 a_ = (f32x4){0.f,0.f,0.f,0.f};                                           \
    int nt_ = w >> 2, mt_ = w & 3;                                                 \
    _Pragma("unroll")                                                              \
    for (int kc_ = 0; kc_ < 8; ++kc_) {                                            \
      short8 af_ = frag(lds, O_XH0, 16 * mt_ + lm, kc_ * 32 + lg * 8, 256);        \
      short8 bf_ = frag(lds, O_WB, 16 * nt_ + lm, kc_ * 32 + lg * 8, 256);         \
      a_ = __builtin_amdgcn_mfma_f32_16x16x32_bf16(af_, bf_, a_, 0, 0, 0);         \
    }                                                                              \
    { int o_ = (OBASE) + 16 * nt_ + lm; float bb_ = (BIAS)[o_];                    \
      _Pragma("unroll")                                                            \
      for (int r_ = 0; r_ < 4; ++r_) {                                             \
        int tok_ = 16 * mt_ + 4 * lg + r_;                                         \
        lds[(ODST) + tok_ * 128 + (o_ ^ ((tok_ & 7) << 3))] = (unsigned short)bf16r(a_[r_] + bb_); \
      } }                                                                          \
    __syncthreads();                                                               \
  } while (0)

#define GEMM128(ACC, XOFF) do {                                                    \
    _Pragma("unroll")                                                              \
    for (int kc_ = 0; kc_ < 4; ++kc_) {                                            \
      short8 af_ = frag(lds, (XOFF), 16 * w + lm, kc_ * 32 + lg * 8, 128);         \
      _Pragma("unroll")                                                            \
      for (int n_ = 0; n_ < 4; ++n_) {                                             \
        short8 bf_ = frag(lds, O_WB, 16 * n_ + lm, kc_ * 32 + lg * 8, 128);        \
        ACC[n_] = __builtin_amdgcn_mfma_f32_16x16x32_bf16(af_, bf_, ACC[n_], 0, 0, 0); \
      } }                                                                          \
  } while (0)

#define CONSUME(ACC, DY, NH) do {                                                  \
    _Pragma("unroll")                                                              \
    for (int n_ = 0; n_ < 4; ++n_) {                                               \
      int nt_ = 4 * (NH) + n_;                                                     \
      int o_ = 16 * nt_ + lm;                                                      \
      float bias_ = bq[o_];                                                        \
      float sd01_ = 0.f, sd23_ = 0.f;                                              \
      _Pragma("unroll")                                                            \
      for (int r_ = 0; r_ < 4; ++r_) {                                             \
        int row_ = 16 * w + 4 * lg + r_;                                           \
        int tok_ = row_ >> 1;                                                      \
        float q_ = ACC[n_][r_] + bias_;                                            \
        float kv_ = ubf(lds[O_K + tok_ * 128 + (o_ ^ ((tok_ & 7) << 3))]);         \
        float t0_ = q_, t1_ = q_ * q_, t2_ = q_ * gw, t3_ = q_ * kv_;              \
        _Pragma("unroll")                                                          \
        for (int d_ = 1; d_ < 16; d_ <<= 1) {                                      \
          t0_ += __shfl_xor(t0_, d_, 64); t1_ += __shfl_xor(t1_, d_, 64);          \
          t2_ += __shfl_xor(t2_, d_, 64); t3_ += __shfl_xor(t3_, d_, 64);          \
        }                                                                          \
        float mn_ = t0_ * 0.0625f;                                                 \
        float rs_ = rsqrtf(t1_ * 0.0625f - mn_ * mn_ + 1e-5f);                     \
        float sdt_ = rs_ * (t2_ - mn_ * S1) + S2;                                  \
        if (r_ < 2) sd01_ += sdt_; else sd23_ += sdt_;                             \
        if (lm == r_) lds[O_LG + ((DY) * 128 + row_) * 8 + nt_] = (unsigned short)bf16r(t3_ * 0.25f); \
      }                                                                            \
      if (lm == 0) smf[(8 * w + 2 * lg) * 8 + nt_]     += sd01_;                   \
      if (lm == 1) smf[(8 * w + 2 * lg + 1) * 8 + nt_] += sd23_;                   \
    } } while (0)

#define COMBINE(ACC, DY, NH) do {                                                  \
    _Pragma("unroll")                                                              \
    for (int n_ = 0; n_ < 4; ++n_) {                                               \
      int nt_ = 4 * (NH) + n_;                                                     \
      int o_ = 16 * nt_ + lm;                                                      \
      float bias_ = bqv[o_];                                                       \
      float cmv_ = cmp[o_];                                                        \
      _Pragma("unroll")                                                            \
      for (int r_ = 0; r_ < 4; ++r_) {                                             \
        int row_ = 16 * w + 4 * lg + r_;                                           \
        int jj_ = row_ >> 1;                                                       \
        float vq_ = ACC[n_][r_] + bias_;                                           \
        float aw_ = ubf(lds[O_LG + ((DY) * 128 + row_) * 8 + nt_]);                \
        float vv_ = ubf(lds[O_V + jj_ * 128 + (o_ ^ ((jj_ & 7) << 3))]);           \
        float wg_ = 1.f / (1.f + __expf(-(smf[jj_ * 8 + nt_] + cmv_)));            \
        float xc_ = (1.f - wg_) * aw_ * vv_ * 4.f + wg_ * vq_;                     \
        lds[O_XC + row_ * 128 + (o_ ^ ((row_ & 7) << 3))] = (unsigned short)bf16r(xc_); \
      } } } while (0)

// ---------------- kernel 3: fused main ----------------
__global__ __launch_bounds__(512, 2) void pafm_v5(
    const float* __restrict__ x_l,  const float* __restrict__ x_r,
    const float* __restrict__ x_lh, const float* __restrict__ x_rh,
    const float* __restrict__ bq,   const float* __restrict__ bqv,
    const float* __restrict__ bk,   const float* __restrict__ bv,
    const float* __restrict__ bp,
    const float* __restrict__ ln_g, const float* __restrict__ ln_b,
    const float* __restrict__ d_ln1_g, const float* __restrict__ d_ln1_b,
    const float* __restrict__ d_wsv,
    const float* __restrict__ ws_cm,
    const unsigned short* __restrict__ wsp,
    float* __restrict__ out) {

    __shared__ unsigned short lds[LDS_U16];
    float* smf = (float*)&lds[O_SM];

    int bid = blockIdx.x;                 // s(1)|b(2)|i0(7)|jb(1)
    int s  = bid >> 10;
    int b  = (bid >> 8) & 3;
    int i0 = (bid >> 1) & 127;
    int j0 = (bid & 1) * 64;

    int t = threadIdx.x, w = t >> 6, l = t & 63, lm = l & 15, lg = l >> 4;

    const float* xlow  = s ? x_r  : x_l;
    const float* xhigh = s ? x_rh : x_lh;
    const float* cmp   = ws_cm + (s * 4 + b) * 128;

    float gw = d_ln1_g[lm] * d_wsv[lm];
    float S1 = gw, S2 = d_ln1_b[lm] * d_wsv[lm];
    #pragma unroll
    for (int d = 1; d < 16; d <<= 1) { S1 += __shfl_xor(S1, d, 64); S2 += __shfl_xor(S2, d, 64); }

    const float* lowb = xlow + ((size_t)(b * 256) * 128 + i0) * 128 + j0;

    smf[t & 511] = 0.f;   // t<512: zero all 512

    // ---- stage xlow, K and V quarters ----
    stageA<64, 256>(lowb, 16384, lds, O_XH0, t);
    __syncthreads();
    KVQ(0,     bk, 0,  O_K); KVQ(8192,  bk, 32, O_K);
    KVQ(16384, bk, 64, O_K); KVQ(24576, bk, 96, O_K);
    KVQ(32768, bv, 0,  O_V); KVQ(40960, bv, 32, O_V);
    KVQ(49152, bv, 64, O_V); KVQ(57344, bv, 96, O_V);

    // ---- stage x_high both dy rows (persist) ----
    {
        const float* hb0 = xhigh + ((size_t)(b * 128) * 256 + (2 * i0)) * 256 + 2 * j0;
        const float* hb1 = hb0 + 256;
        stageA<128, 128>(hb0, 65536, lds, O_XH0, t);
        stageA<128, 128>(hb1, 65536, lds, O_XH1, t);
    }
    __syncthreads();

    // ---- pass 1: Q + logits + DANE, weight-half hoisted over dy ----
    {
        stageW16(wsp + 65536, lds, t);          // WQs half 0
        __syncthreads();
        { f32x4 q4[4]; ZERO4(q4); GEMM128(q4, O_XH0); CONSUME(q4, 0, 0); }
        { f32x4 q4[4]; ZERO4(q4); GEMM128(q4, O_XH1); CONSUME(q4, 1, 0); }
        __syncthreads();
        stageW16(wsp + 65536 + 8192, lds, t);   // WQs half 1
        __syncthreads();
        { f32x4 q4[4]; ZERO4(q4); GEMM128(q4, O_XH0); CONSUME(q4, 0, 1); }
        { f32x4 q4[4]; ZERO4(q4); GEMM128(q4, O_XH1); CONSUME(q4, 1, 1); }
        __syncthreads();
    }

    // ---- softmax over 4 px + finalize sm (512 items) ----
    {
        int jj = t >> 3, h = t & 7;
        int r00 = (2 * jj) * 8 + h,       r01 = (2 * jj + 1) * 8 + h;
        int r10 = (128 + 2 * jj) * 8 + h, r11 = (128 + 2 * jj + 1) * 8 + h;
        float l00 = ubf(lds[O_LG + r00]), l01 = ubf(lds[O_LG + r01]);
        float l10 = ubf(lds[O_LG + r10]), l11 = ubf(lds[O_LG + r11]);
        float mx = fmaxf(fmaxf(l00, l01), fmaxf(l10, l11));
        float e00 = __expf(l00 - mx), e01 = __expf(l01 - mx);
        float e10 = __expf(l10 - mx), e11 = __expf(l11 - mx);
        float inv = 1.f / (e00 + e01 + e10 + e11);
        lds[O_LG + r00] = (unsigned short)bf16r(e00 * inv);
        lds[O_LG + r01] = (unsigned short)bf16r(e01 * inv);
        lds[O_LG + r10] = (unsigned short)bf16r(e10 * inv);
        lds[O_LG + r11] = (unsigned short)bf16r(e11 * inv);
        smf[jj * 8 + h] *= 0.25f;
    }
    __syncthreads();

    // ---- pass 2 per dy: VQ -> combine -> P -> LN -> store ----
    for (int dy = 0; dy < 2; ++dy) {
        int xoff = dy ? O_XH1 : O_XH0;
        stageW16(wsp + 81920, lds, t);          // WQVs half 0
        __syncthreads();
        { f32x4 v4_[4]; ZERO4(v4_); GEMM128(v4_, xoff); COMBINE(v4_, dy, 0); }
        __syncthreads();
        stageW16(wsp + 81920 + 8192, lds, t);   // WQVs half 1
        __syncthreads();
        { f32x4 v4_[4]; ZERO4(v4_); GEMM128(v4_, xoff); COMBINE(v4_, dy, 1); }
        __syncthreads();

        f32x4 pA[4], pB[4];
        stageW16(wsp + 98304, lds, t);          // WPs half 0
        __syncthreads();
        ZERO4(pA); GEMM128(pA, O_XC);
        __syncthreads();
        stageW16(wsp + 98304 + 8192, lds, t);   // WPs half 1
        __syncthreads();
        ZERO4(pB); GEMM128(pB, O_XC);
        __syncthreads();                        // XC reads done; yn may overwrite

        float mean_[4], rstd_[4];
        #pragma unroll
        for (int r = 0; r < 4; ++r) {
            float ps = 0.f, pq = 0.f;
            #pragma unroll
            for (int n = 0; n < 4; ++n) {
                float y0 = pA[n][r] + bp[16 * n + lm];
                float y1 = pB[n][r] + bp[64 + 16 * n + lm];
                ps += y0 + y1;
                pq = fmaf(y0, y0, pq); pq = fmaf(y1, y1, pq);
            }
            #pragma unroll
            for (int d = 1; d < 16; d <<= 1) { ps += __shfl_xor(ps, d, 64); pq += __shfl_xor(pq, d, 64); }
            float mn = ps * (1.f / 128.f);
            mean_[r] = mn;
            rstd_[r] = rsqrtf(pq * (1.f / 128.f) - mn * mn + 1e-5f);
        }
        #pragma unroll
        for (int n = 0; n < 4; ++n) {
            int oA = 16 * n + lm, oB = 64 + 16 * n + lm;
            float gA = ln_g[oA], bA = ln_b[oA], biA = bp[oA];
            float gB = ln_g[oB], bB = ln_b[oB], biB = bp[oB];
            #pragma unroll
            for (int r = 0; r < 4; ++r) {
                int row = 16 * w + 4 * lg + r;
                float ynA = (pA[n][r] + biA - mean_[r]) * rstd_[r] * gA + bA;
                float ynB = (pB[n][r] + biB - mean_[r]) * rstd_[r] * gB + bB;
                lds[O_XC + row * 128 + (oA ^ ((row & 31) << 2))] = (unsigned short)bf16r(ynA);
                lds[O_XC + row * 128 + (oB ^ ((row & 31) << 2))] = (unsigned short)bf16r(ynB);
            }
        }
        __syncthreads();
        // coalesced store + residual from LDS (bf16 x_high)
        {
            float* ob = out + (size_t)s * 33554432
                      + ((size_t)(b * 128)) * 65536 + (size_t)(2 * i0 + dy) * 256 + 2 * j0;
            int ph = t & 127, oq = t >> 7;
            #pragma unroll 8
            for (int it = 0; it < 32; ++it) {
                int oo = 4 * it + oq;
                float yn = ubf(lds[O_XC + ph * 128 + (oo ^ ((ph & 31) << 2))]);
                float xh = ubf(lds[xoff + ph * 128 + (oo ^ ((ph & 7) << 3))]);
                ob[(size_t)oo * 65536 + ph] = xh + yn;
            }
        }
        __syncthreads();    // protect XC/WB before next dy
    }
}

extern "C" void kernel_launch(void* const* d_in, const int* in_sizes, int n_in,
                              void* d_out, int out_size, void* d_ws, size_t ws_size,
                              hipStream_t stream) {
    const float* x_l   = (const float*)d_in[0];
    const float* x_r   = (const float*)d_in[1];
    const float* x_lh  = (const float*)d_in[2];
    const float* x_rh  = (const float*)d_in[3];
    const float* Wq    = (const float*)d_in[4];
    const float* bq    = (const float*)d_in[5];
    const float* Wqv   = (const float*)d_in[6];
    const float* bqv   = (const float*)d_in[7];
    const float* Wk    = (const float*)d_in[8];
    const float* bk    = (const float*)d_in[9];
    const float* Wv    = (const float*)d_in[10];
    const float* bv    = (const float*)d_in[11];
    const float* Wp    = (const float*)d_in[12];
    const float* bp    = (const float*)d_in[13];
    const float* ln_g  = (const float*)d_in[14];
    const float* ln_b  = (const float*)d_in[15];
    const float* dln1g = (const float*)d_in[16];
    const float* dln1b = (const float*)d_in[17];
    const float* d_wsv = (const float*)d_in[18];
    const float* d_w1  = (const float*)d_in[19];
    const float* dln2g = (const float*)d_in[20];
    const float* dln2b = (const float*)d_in[21];
    const float* d_w2  = (const float*)d_in[22];

    float* out = (float*)d_out;
    float* ws_mean = (float*)d_ws;                                 // 2048 f
    float* ws_cm   = ws_mean + 2048;                               // 1024 f
    unsigned short* wsp = (unsigned short*)((char*)d_ws + 16384);  // 224 KB bf16 pool

    mean_kernel<<<2048, 256, 0, stream>>>(x_l, x_r, ws_mean);
    wprep<<<112, 256, 0, stream>>>(Wq, Wqv, Wk, Wv, Wp, wsp);
    cm_kernel<<<8, 128, 0, stream>>>(ws_mean, ws_cm, Wk, bk, d_w1, dln2g, dln2b, d_w2);
    pafm_v5<<<2048, 512, 0, stream>>>(x_l, x_r, x_lh, x_rh,
                                      bq, bqv, bk, bv, bp, ln_g, ln_b,
                                      dln1g, dln1b, d_wsv, ws_cm, wsp, out);
}